// Round 15
// baseline (1076.463 us; speedup 1.0000x reference)
//
#include <hip/hip_runtime.h>
#include <hip/hip_bf16.h>
#include <cmath>

#define B_  16
#define S_  512
#define D_  512
#define F_  2048
#define L_  6
#define MT  8192  // B_*S_ rows

typedef __attribute__((ext_vector_type(8))) __bf16 bf16x8;
typedef __attribute__((ext_vector_type(4))) float  f32x4;

__device__ __forceinline__ unsigned short f2bf(float f) {
  return __builtin_bit_cast(unsigned short, __float2bfloat16(f));
}

__device__ __forceinline__ void gload16(const void* g, void* l) {
  __builtin_amdgcn_global_load_lds(
      (const __attribute__((address_space(1))) void*)g,
      (__attribute__((address_space(3))) void*)l, 16, 0, 0);
}

// ------------------------------------------------------------- embed + PE
__global__ void embed_pe_kernel(const int* __restrict__ x,
                                const int* __restrict__ blen,
                                const float* __restrict__ emb,
                                float* __restrict__ h,
                                unsigned short* __restrict__ hbf) {
  int bs = blockIdx.x;
  int b = bs >> 9, s = bs & 511;
  int tok = x[bs];
  bool pe = s < blen[b];
  const float* er = emb + (long)tok * D_;
  long rb = (long)bs * D_;
  for (int d = threadIdx.x; d < D_; d += 256) {
    float e = er[d];
    if (pe) {
      float ex = (2.0f * (float)d) / 512.0f;
      float ang = (float)s / powf(10000.0f, ex);
      e += (d & 1) ? cosf(ang) : sinf(ang);
    }
    h[rb + d] = e;
    hbf[rb + d] = f2bf(e);
  }
}

// ------------------------------------------------------------- pad-mask bits
__global__ void mask_build_kernel(const int* __restrict__ x,
                                  unsigned int* __restrict__ mw) {
  int t = threadIdx.x;            // 256 threads, 1 block
  int b = t >> 4, wd = t & 15;
  unsigned int m = 0;
  for (int j = 0; j < 32; j++)
    if (x[b * 512 + wd * 32 + j] == 0) m |= (1u << j);
  mw[b * 16 + wd] = m;
}

// --------------------------------------------- weight transpose fp32->bf16
__global__ __launch_bounds__(256)
void wconv_kernel(const float* __restrict__ in, unsigned short* __restrict__ out,
                  int K, int N, long inls, long outls) {
  __shared__ float tile[32][33];
  const float* ip = in + (long)blockIdx.z * inls;
  unsigned short* op = out + (long)blockIdx.z * outls;
  int k0 = blockIdx.y * 32, n0 = blockIdx.x * 32;
  int tx = threadIdx.x & 31, ty = threadIdx.x >> 5;
  for (int i = ty; i < 32; i += 8) tile[i][tx] = ip[(long)(k0 + i) * N + n0 + tx];
  __syncthreads();
  for (int i = ty; i < 32; i += 8) op[(long)(n0 + i) * K + k0 + tx] = f2bf(tile[tx][i]);
}

// ------------------------------------------------------------- bf16 MFMA GEMM
// C[M,N] = A[M,K] @ Bt[N,K]^T. Tile 64x128, BK=32, 4 waves (each 64x32 out).
// LDS 24KB (2-buf) -> 6 blocks/CU resident: latency-bound regime, TLP wins
// over tile size (r7/r8 evidence: Wo/W2 58->~35us with the same change).
// Depth-1 counted-vmcnt pipeline.
template<int BMv, int MINW>
__global__ __launch_bounds__(256, MINW)
void gemm_bf16(const unsigned short* __restrict__ A,
               const unsigned short* __restrict__ Bt,
               const float* __restrict__ bias,
               float* __restrict__ C, unsigned short* __restrict__ Cbf,
               int M, int N, int K, int relu, int qkv) {
  constexpr int MFR = 4;
  constexpr int NFR = (BMv == 128) ? 4 : 2;
  __shared__ unsigned short Al[2][BMv * 32];
  __shared__ unsigned short Bl[2][128 * 32];
  int t = threadIdx.x;
  int lane = t & 63, wid = t >> 6;

  int flat = blockIdx.y * gridDim.x + blockIdx.x;
  int npx = (gridDim.x * gridDim.y) >> 3;
  int w = (flat & 7) * npx + (flat >> 3);
  int bx = w % gridDim.x, by = w / gridDim.x;

  int rbase = by * BMv, cbase = bx * 128;
  int wr = (BMv == 128) ? (wid >> 1) * 64 : 0;
  int wc = (BMv == 128) ? (wid & 1) * 64 : wid * 32;

  f32x4 acc[MFR][NFR];
#pragma unroll
  for (int i = 0; i < MFR; i++)
#pragma unroll
    for (int j = 0; j < NFR; j++) acc[i][j] = (f32x4){0.f, 0.f, 0.f, 0.f};

  int srow = t >> 2;
  int sc = (((t & 3) ^ ((t >> 3) & 3)) << 3);
  const unsigned short* Ag  = A  + (long)(rbase + srow) * K + sc;
  const unsigned short* Ag2 = A  + (long)(rbase + 64 + srow) * K + sc;
  const unsigned short* Bg  = Bt + (long)(cbase + srow) * K + sc;
  const unsigned short* Bg2 = Bt + (long)(cbase + 64 + srow) * K + sc;

  auto stage = [&](int bi, int kt) {
    gload16(Ag + kt, &Al[bi][t * 8]);
    if constexpr (BMv == 128) gload16(Ag2 + kt, &Al[bi][2048 + t * 8]);
    gload16(Bg + kt, &Bl[bi][t * 8]);
    gload16(Bg2 + kt, &Bl[bi][2048 + t * 8]);
  };

  int fr = lane & 15;
  int c4 = lane >> 4;

  int nt = K >> 5;
  stage(0, 0);
  int cur = 0;
  for (int tt = 0; tt < nt; ++tt) {
    if (tt + 1 < nt) {
      stage(cur ^ 1, (tt + 1) << 5);
      if constexpr (BMv == 128)
        asm volatile("s_waitcnt vmcnt(4)" ::: "memory");
      else
        asm volatile("s_waitcnt vmcnt(3)" ::: "memory");
    } else {
      asm volatile("s_waitcnt vmcnt(0)" ::: "memory");
    }
    __builtin_amdgcn_s_barrier();

    bf16x8 a[MFR], b[NFR];
#pragma unroll
    for (int m = 0; m < MFR; m++) {
      int R = wr + m * 16 + fr;
      a[m] = *(const bf16x8*)&Al[cur][R * 32 + ((c4 ^ ((R >> 1) & 3)) << 3)];
    }
#pragma unroll
    for (int n = 0; n < NFR; n++) {
      int R = wc + n * 16 + fr;
      b[n] = *(const bf16x8*)&Bl[cur][R * 32 + ((c4 ^ ((R >> 1) & 3)) << 3)];
    }
#pragma unroll
    for (int m = 0; m < MFR; m++)
#pragma unroll
      for (int n = 0; n < NFR; n++)
        acc[m][n] = __builtin_amdgcn_mfma_f32_16x16x32_bf16(a[m], b[n], acc[m][n], 0, 0, 0);
    __builtin_amdgcn_s_barrier();
    cur ^= 1;
  }

  if (qkv) {
    // Cbf = q_bf; k_bf at +4194304; vt_bf at +8388608 (transposed per block)
#pragma unroll
    for (int m = 0; m < MFR; m++) {
#pragma unroll
      for (int n = 0; n < NFR; n++) {
        int col = cbase + wc + n * 16 + fr;
#pragma unroll
        for (int j = 0; j < 4; j++) {
          long row = rbase + wr + m * 16 + (lane >> 4) * 4 + j;
          unsigned short v = f2bf(acc[m][n][j]);
          if (col < 1024) {
            Cbf[(col < 512 ? 0L : 4194304L - 512L) + row * 512 + col] = v;
          } else {
            int cc = col - 1024;
            Cbf[8388608L + (row >> 6) * 32768 + (long)(cc & 63) * 512 +
                ((row & 63) << 3) + (cc >> 6)] = v;
          }
        }
      }
    }
  } else {
#pragma unroll
    for (int m = 0; m < MFR; m++) {
#pragma unroll
      for (int n = 0; n < NFR; n++) {
        int col = cbase + wc + n * 16 + fr;
        float bv = bias ? bias[col] : 0.0f;
#pragma unroll
        for (int j = 0; j < 4; j++) {
          long row = rbase + wr + m * 16 + (lane >> 4) * 4 + j;
          float v = acc[m][n][j] + bv;
          if (relu) v = fmaxf(v, 0.0f);
          if (C)   C[row * N + col] = v;
          if (Cbf) Cbf[row * N + col] = f2bf(v);
        }
      }
    }
  }
}

// ------------------------------------------------------------- MFMA attention
// SPLIT-K: 512 threads = 8 waves = 4 q-groups x 2 k-halves (round-14 state).
__global__ __launch_bounds__(512, 4)
void attn_mfma(const unsigned short* __restrict__ qbf,
               const unsigned short* __restrict__ kbf,
               const unsigned short* __restrict__ vtbf,
               const unsigned int* __restrict__ maskw,
               unsigned short* __restrict__ ctxbf) {
  __shared__ unsigned short sb[4][8192];   // 4 x 16KB chunk buffers (buf = chunk)
  __shared__ float red[2][8][64];          // partial max / sum exchange
  int t = threadIdx.x;
  int lane = t & 63, w = t >> 6;           // 8 waves
  int qg = w & 3, kh = w >> 2;             // q-group, k-half
  int c = lane & 15, h = lane >> 4;

  int flat = blockIdx.y * 8 + blockIdx.x;  // grid (8, 128)
  int wk = (flat & 7) * 128 + (flat >> 3); // XCD swizzle: 16 bh per XCD
  int qt = wk & 7, bh = wk >> 3;

  long bhb = (long)bh << 15;
  int mb = bh & 15;

  unsigned int mwa[16];
#pragma unroll
  for (int i = 0; i < 16; i++)
    mwa[i] = (unsigned int)__builtin_amdgcn_readfirstlane((int)maskw[mb * 16 + i]);

  const bf16x8* qp = (const bf16x8*)(qbf + bhb + (long)(qt * 64 + qg * 16 + c) * 64);
  bf16x8 qf0 = qp[h], qf1 = qp[h + 4];

  auto stageK = [&](int gc) {
#pragma unroll
    for (int i = 0; i < 2; i++) {
      int idx = t + 512 * i;
      int kr = idx >> 3, g = idx & 7;
      gload16(kbf + bhb + (long)(gc * 128 + kr) * 64 + ((g ^ (kr & 7)) << 3),
              &sb[gc][idx * 8]);
    }
  };
  auto stageV = [&](int gc) {
#pragma unroll
    for (int i = 0; i < 2; i++) {
      int idx = t + 512 * i;
      int d = idx >> 4, g = idx & 15;
      gload16(vtbf + bhb + (long)d * 512 + gc * 128 + ((g ^ (d & 15)) << 3),
              &sb[gc][idx * 8]);
    }
  };

  stageK(0); stageK(2); stageK(1); stageK(3);

  f32x4 acc[16];
#pragma unroll
  for (int F = 0; F < 16; F++) acc[F] = (f32x4){0.f, 0.f, 0.f, 0.f};

#pragma unroll
  for (int lc = 0; lc < 2; lc++) {
    if (lc == 0) asm volatile("s_waitcnt vmcnt(4)" ::: "memory");
    else         asm volatile("s_waitcnt vmcnt(0)" ::: "memory");
    __builtin_amdgcn_s_barrier();
    const unsigned short* kb = sb[kh * 2 + lc];
#pragma unroll
    for (int f = 0; f < 8; f++) {
      int R = f * 16 + c;
      int ro = R * 64;
      bf16x8 a0 = *(const bf16x8*)&kb[ro + ((h ^ (R & 7)) << 3)];
      bf16x8 a1 = *(const bf16x8*)&kb[ro + (((h + 4) ^ (R & 7)) << 3)];
      acc[lc * 8 + f] = __builtin_amdgcn_mfma_f32_16x16x32_bf16(a0, qf0, acc[lc * 8 + f], 0, 0, 0);
      acc[lc * 8 + f] = __builtin_amdgcn_mfma_f32_16x16x32_bf16(a1, qf1, acc[lc * 8 + f], 0, 0, 0);
    }
  }
  __builtin_amdgcn_s_barrier();

  stageV(0); stageV(2); stageV(1); stageV(3);

#pragma unroll
  for (int F = 0; F < 16; F++) {
    int gc = kh * 2 + (F >> 3), f = F & 7;
    unsigned int nib = (mwa[gc * 4 + (f >> 1)] >> (((f & 1) << 4) + (h << 2))) & 0xFu;
#pragma unroll
    for (int j = 0; j < 4; j++)
      acc[F][j] = (nib & (1u << j)) ? -1e9f : acc[F][j] * 0.125f;
  }

  float mx = -3.0e38f;
#pragma unroll
  for (int F = 0; F < 16; F++)
#pragma unroll
    for (int j = 0; j < 4; j++) mx = fmaxf(mx, acc[F][j]);
  mx = fmaxf(mx, __shfl_xor(mx, 16));
  mx = fmaxf(mx, __shfl_xor(mx, 32));
  red[0][w][lane] = mx;
  __builtin_amdgcn_s_barrier();
  mx = fmaxf(mx, red[0][w ^ 4][lane]);

  float sm = 0.f;
  unsigned int pk[32];
#pragma unroll
  for (int F = 0; F < 16; F++) {
    float e0 = __expf(acc[F][0] - mx); sm += e0;
    float e1 = __expf(acc[F][1] - mx); sm += e1;
    float e2 = __expf(acc[F][2] - mx); sm += e2;
    float e3 = __expf(acc[F][3] - mx); sm += e3;
    pk[2 * F]     = (unsigned int)f2bf(e0) | ((unsigned int)f2bf(e1) << 16);
    pk[2 * F + 1] = (unsigned int)f2bf(e2) | ((unsigned int)f2bf(e3) << 16);
  }
  sm += __shfl_xor(sm, 16);
  sm += __shfl_xor(sm, 32);
  red[1][w][lane] = sm;
  __builtin_amdgcn_s_barrier();
  sm += red[1][w ^ 4][lane];

  float rs0 = 1.0f / __shfl(sm, h * 4 + 0);
  float rs1 = 1.0f / __shfl(sm, h * 4 + 1);
  float rs2 = 1.0f / __shfl(sm, h * 4 + 2);
  float rs3 = 1.0f / __shfl(sm, h * 4 + 3);

  f32x4 o[4];
#pragma unroll
  for (int n = 0; n < 4; n++) o[n] = (f32x4){0.f, 0.f, 0.f, 0.f};
  int l0 = c | ((lane & 16) << 1);
  int l1 = l0 + 16;
  bool hb = (lane & 32) != 0;

#pragma unroll
  for (int lc = 0; lc < 2; lc++) {
    if (lc == 0) asm volatile("s_waitcnt vmcnt(4)" ::: "memory");
    else         asm volatile("s_waitcnt vmcnt(0)" ::: "memory");
    __builtin_amdgcn_s_barrier();
    const unsigned short* vbuf = sb[kh * 2 + lc];
#pragma unroll
    for (int sub = 0; sub < 4; sub++) {
      int kt4 = (lc * 4 + sub) * 4;
      unsigned int a0 = __shfl((int)pk[kt4],     l0);
      unsigned int a1 = __shfl((int)pk[kt4 + 1], l0);
      unsigned int a2 = __shfl((int)pk[kt4],     l1);
      unsigned int a3 = __shfl((int)pk[kt4 + 1], l1);
      unsigned int b0 = __shfl((int)pk[kt4 + 2], l0);
      unsigned int b1 = __shfl((int)pk[kt4 + 3], l0);
      unsigned int b2 = __shfl((int)pk[kt4 + 2], l1);
      unsigned int b3 = __shfl((int)pk[kt4 + 3], l1);
      uint4 aw;
      aw.x = hb ? b0 : a0; aw.y = hb ? b1 : a1;
      aw.z = hb ? b2 : a2; aw.w = hb ? b3 : a3;
      bf16x8 af = __builtin_bit_cast(bf16x8, aw);
#pragma unroll
      for (int n = 0; n < 4; n++) {
        int dl = n * 16 + c;
        bf16x8 vf = *(const bf16x8*)&vbuf[dl * 128 + (((sub * 4 + h) ^ (dl & 15)) << 3)];
        o[n] = __builtin_amdgcn_mfma_f32_16x16x32_bf16(af, vf, o[n], 0, 0, 0);
      }
    }
  }
  __builtin_amdgcn_s_barrier();

  float* osb = (float*)sb;
  if (kh) {
#pragma unroll
    for (int n = 0; n < 4; n++)
#pragma unroll
      for (int j = 0; j < 4; j++)
        osb[((w - 4) * 64 + lane) * 16 + n * 4 + j] = o[n][j];
  }
  __builtin_amdgcn_s_barrier();
  if (!kh) {
    unsigned short* cp = ctxbf + bhb + (long)(qt * 64 + qg * 16) * 64;
#pragma unroll
    for (int n = 0; n < 4; n++) {
      float t0 = o[n][0] + osb[(w * 64 + lane) * 16 + n * 4 + 0];
      float t1 = o[n][1] + osb[(w * 64 + lane) * 16 + n * 4 + 1];
      float t2 = o[n][2] + osb[(w * 64 + lane) * 16 + n * 4 + 2];
      float t3 = o[n][3] + osb[(w * 64 + lane) * 16 + n * 4 + 3];
      cp[(h * 4 + 0) * 64 + n * 16 + c] = f2bf(t0 * rs0);
      cp[(h * 4 + 1) * 64 + n * 16 + c] = f2bf(t1 * rs1);
      cp[(h * 4 + 2) * 64 + n * 16 + c] = f2bf(t2 * rs2);
      cp[(h * 4 + 3) * 64 + n * 16 + c] = f2bf(t3 * rs3);
    }
  }
}

// ------------------------------------------------------------- LayerNorm(a+r)
__global__ __launch_bounds__(256)
void ln_kernel(const float* __restrict__ a, const float* __restrict__ r,
               const float* __restrict__ g, const float* __restrict__ be,
               float* __restrict__ out, unsigned short* __restrict__ outbf) {
  int w = threadIdx.x >> 6, lane = threadIdx.x & 63;
  long row = (long)blockIdx.x * 4 + w;
  long base = row * D_ + lane * 8;
  float4 a0 = *(const float4*)(a + base);
  float4 a1 = *(const float4*)(a + base + 4);
  float4 r0 = *(const float4*)(r + base);
  float4 r1 = *(const float4*)(r + base + 4);
  float xv[8] = {a0.x + r0.x, a0.y + r0.y, a0.z + r0.z, a0.w + r0.w,
                 a1.x + r1.x, a1.y + r1.y, a1.z + r1.z, a1.w + r1.w};
  float s = 0;
#pragma unroll
  for (int e = 0; e < 8; e++) s += xv[e];
#pragma unroll
  for (int off = 1; off < 64; off <<= 1) s += __shfl_xor(s, off);
  float m = s * (1.0f / 512.0f);
  float vs = 0;
#pragma unroll
  for (int e = 0; e < 8; e++) { float d = xv[e] - m; vs += d * d; }
#pragma unroll
  for (int off = 1; off < 64; off <<= 1) vs += __shfl_xor(vs, off);
  float rstd = 1.0f / sqrtf(vs * (1.0f / 512.0f) + 1e-5f);
  int gb = lane * 8;
  float o[8];
#pragma unroll
  for (int e = 0; e < 8; e++) o[e] = (xv[e] - m) * rstd * g[gb + e] + be[gb + e];
  *(float4*)(out + base)     = make_float4(o[0], o[1], o[2], o[3]);
  *(float4*)(out + base + 4) = make_float4(o[4], o[5], o[6], o[7]);
  ushort4 u0, u1;
  u0.x = f2bf(o[0]); u0.y = f2bf(o[1]); u0.z = f2bf(o[2]); u0.w = f2bf(o[3]);
  u1.x = f2bf(o[4]); u1.y = f2bf(o[5]); u1.z = f2bf(o[6]); u1.w = f2bf(o[7]);
  *(ushort4*)(outbf + base)     = u0;
  *(ushort4*)(outbf + base + 4) = u1;
}

// ------------------------------------------------------------- launch
extern "C" void kernel_launch(void* const* d_in, const int* in_sizes, int n_in,
                              void* d_out, int out_size, void* d_ws, size_t ws_size,
                              hipStream_t stream) {
  const int*   x    = (const int*)d_in[0];
  const int*   blen = (const int*)d_in[1];
  const float* emb  = (const float*)d_in[2];
  const float* Wq   = (const float*)d_in[3];
  const float* Wk   = (const float*)d_in[4];
  const float* Wv   = (const float*)d_in[5];
  const float* Wo   = (const float*)d_in[6];
  const float* bo   = (const float*)d_in[7];
  const float* ln1g = (const float*)d_in[8];
  const float* ln1b = (const float*)d_in[9];
  const float* W1   = (const float*)d_in[10];
  const float* b1   = (const float*)d_in[11];
  const float* W2   = (const float*)d_in[12];
  const float* b2   = (const float*)d_in[13];
  const float* ln2g = (const float*)d_in[14];
  const float* ln2b = (const float*)d_in[15];
  float* out = (float*)d_out;

  float* ws_f = (float*)d_ws;
  const long M4 = 4194304L;
  float* h   = ws_f;                 // 4M f32
  float* tmp = ws_f + M4;            // 4M f32
  unsigned short* U = (unsigned short*)(ws_f + 2 * M4);
  unsigned short* h_bf   = U;                    // 4M
  unsigned short* q_bf   = U + M4;               // 4M (k,vt,ctx follow contiguously)
  unsigned short* k_bf   = U + 2 * M4;
  unsigned short* vt_bf  = U + 3 * M4;
  unsigned short* ctx_bf = U + 4 * M4;
  unsigned short* mid_bf = q_bf;                 // [8192][2048] aliases q..ctx
  unsigned short* Wqkvt  = U + 5 * M4;           // 6*1536*512
  unsigned short* Wot    = Wqkvt + 6L * 1536 * 512;
  unsigned short* W1t    = Wot   + 6L * 512 * 512;
  unsigned short* W2t    = W1t   + 6L * 2048 * 512;
  unsigned int*   maskw  = (unsigned int*)(W2t + 6L * 512 * 2048);

  wconv_kernel<<<dim3(16, 16, 6), 256, 0, stream>>>(Wq, Wqkvt,            512, 512,  262144L, 786432L);
  wconv_kernel<<<dim3(16, 16, 6), 256, 0, stream>>>(Wk, Wqkvt + 262144,   512, 512,  262144L, 786432L);
  wconv_kernel<<<dim3(16, 16, 6), 256, 0, stream>>>(Wv, Wqkvt + 524288,   512, 512,  262144L, 786432L);
  wconv_kernel<<<dim3(16, 16, 6), 256, 0, stream>>>(Wo, Wot,              512, 512,  262144L, 262144L);
  wconv_kernel<<<dim3(64, 16, 6), 256, 0, stream>>>(W1, W1t,              512, 2048, 1048576L, 1048576L);
  wconv_kernel<<<dim3(16, 64, 6), 256, 0, stream>>>(W2, W2t,              2048, 512, 1048576L, 1048576L);
  mask_build_kernel<<<1, 256, 0, stream>>>(x, maskw);
  embed_pe_kernel<<<MT, 256, 0, stream>>>(x, blen, emb, h, h_bf);

  dim3 gqkv(12, 128), g2048(16, 128), g512b(4, 128), gattn(8, 128);

  for (int l = 0; l < L_; l++) {
    const unsigned short* wqkv = Wqkvt + (long)l * 1536 * 512;
    const unsigned short* wo   = Wot   + (long)l * 512 * 512;
    const unsigned short* w1   = W1t   + (long)l * 2048 * 512;
    const unsigned short* w2   = W2t   + (long)l * 512 * 2048;

    gemm_bf16<64, 4><<<gqkv, 256, 0, stream>>>(h_bf, wqkv, nullptr, nullptr, q_bf,
                                               MT, 1536, 512, 0, 1);
    attn_mfma<<<gattn, 512, 0, stream>>>(q_bf, k_bf, vt_bf, maskw, ctx_bf);
    gemm_bf16<64, 4><<<g512b, 256, 0, stream>>>(ctx_bf, wo, bo + (long)l * D_, tmp, nullptr,
                                                MT, 512, 512, 0, 0);
    ln_kernel<<<MT / 4, 256, 0, stream>>>(h, tmp, ln1g + (long)l * D_,
                                          ln1b + (long)l * D_, h, h_bf);
    gemm_bf16<64, 4><<<g2048, 256, 0, stream>>>(h_bf, w1, b1 + (long)l * F_, nullptr, mid_bf,
                                                MT, 2048, 512, 1, 0);
    gemm_bf16<64, 4><<<g512b, 256, 0, stream>>>(mid_bf, w2, b2 + (long)l * D_, tmp, nullptr,
                                                MT, 512, 2048, 0, 0);
    ln_kernel<<<MT / 4, 256, 0, stream>>>(h, tmp, ln2g + (long)l * D_,
                                          ln2b + (long)l * D_,
                                          (l == L_ - 1) ? out : h, h_bf);
  }
}

// Round 17
// 922.366 us; speedup vs baseline: 1.1671x; 1.1671x over previous
//
#include <hip/hip_runtime.h>
#include <hip/hip_bf16.h>
#include <cmath>

#define B_  16
#define S_  512
#define D_  512
#define F_  2048
#define L_  6
#define MT  8192  // B_*S_ rows

typedef __attribute__((ext_vector_type(8))) __bf16 bf16x8;
typedef __attribute__((ext_vector_type(4))) float  f32x4;

__device__ __forceinline__ unsigned short f2bf(float f) {
  return __builtin_bit_cast(unsigned short, __float2bfloat16(f));
}

__device__ __forceinline__ void gload16(const void* g, void* l) {
  __builtin_amdgcn_global_load_lds(
      (const __attribute__((address_space(1))) void*)g,
      (__attribute__((address_space(3))) void*)l, 16, 0, 0);
}

// ------------------------------------------------------------- embed + PE
__global__ void embed_pe_kernel(const int* __restrict__ x,
                                const int* __restrict__ blen,
                                const float* __restrict__ emb,
                                float* __restrict__ h,
                                unsigned short* __restrict__ hbf) {
  int bs = blockIdx.x;
  int b = bs >> 9, s = bs & 511;
  int tok = x[bs];
  bool pe = s < blen[b];
  const float* er = emb + (long)tok * D_;
  long rb = (long)bs * D_;
  for (int d = threadIdx.x; d < D_; d += 256) {
    float e = er[d];
    if (pe) {
      float ex = (2.0f * (float)d) / 512.0f;
      float ang = (float)s / powf(10000.0f, ex);
      e += (d & 1) ? cosf(ang) : sinf(ang);
    }
    h[rb + d] = e;
    hbf[rb + d] = f2bf(e);
  }
}

// ------------------------------------------------------------- pad-mask bits
__global__ void mask_build_kernel(const int* __restrict__ x,
                                  unsigned int* __restrict__ mw) {
  int t = threadIdx.x;            // 256 threads, 1 block
  int b = t >> 4, wd = t & 15;
  unsigned int m = 0;
  for (int j = 0; j < 32; j++)
    if (x[b * 512 + wd * 32 + j] == 0) m |= (1u << j);
  mw[b * 16 + wd] = m;
}

// --------------------------------------------- weight transpose fp32->bf16
__global__ __launch_bounds__(256)
void wconv_kernel(const float* __restrict__ in, unsigned short* __restrict__ out,
                  int K, int N, long inls, long outls) {
  __shared__ float tile[32][33];
  const float* ip = in + (long)blockIdx.z * inls;
  unsigned short* op = out + (long)blockIdx.z * outls;
  int k0 = blockIdx.y * 32, n0 = blockIdx.x * 32;
  int tx = threadIdx.x & 31, ty = threadIdx.x >> 5;
  for (int i = ty; i < 32; i += 8) tile[i][tx] = ip[(long)(k0 + i) * N + n0 + tx];
  __syncthreads();
  for (int i = ty; i < 32; i += 8) op[(long)(n0 + i) * K + k0 + tx] = f2bf(tile[tx][i]);
}

// ------------------------------------------------- v row-major -> vt per block
// vt[bh][dh][kv] = v_flat[bh*32768 + kv*64 + dh]. FIXED: full 16-ushort load
// per thread (two uint4s) and 72-ushort row stride (16B-aligned rows).
__global__ __launch_bounds__(256)
void vtrans_kernel(const unsigned short* __restrict__ v,
                   unsigned short* __restrict__ vt) {
  __shared__ unsigned short tl[64][72];
  int bh = blockIdx.x;
  const unsigned short* ip = v + (long)bh * 32768;
  unsigned short* op = vt + (long)bh * 32768;
  int t = threadIdx.x;
  int kv = t >> 2, g = t & 3;
  int dh = t >> 2, q4 = t & 3;
  for (int c0 = 0; c0 < 512; c0 += 64) {
    __syncthreads();
    *(uint4*)&tl[kv][g * 16]     = *(const uint4*)&ip[(long)(c0 + kv) * 64 + g * 16];
    *(uint4*)&tl[kv][g * 16 + 8] = *(const uint4*)&ip[(long)(c0 + kv) * 64 + g * 16 + 8];
    __syncthreads();
    unsigned short tmp[16];
#pragma unroll
    for (int e = 0; e < 16; e++) tmp[e] = tl[q4 * 16 + e][dh];
    *(uint4*)&op[(long)dh * 512 + c0 + q4 * 16]     = *(uint4*)&tmp[0];
    *(uint4*)&op[(long)dh * 512 + c0 + q4 * 16 + 8] = *(uint4*)&tmp[8];
  }
}

// ------------------------------------------------------------- bf16 MFMA GEMM
// C[M,N] = A[M,K] @ Bt[N,K]^T. Tile BMv x 128, BK=32, 4 waves.
// 2-buffer depth-1 counted-vmcnt pipeline (r12-best) + LDS-staged vectorized
// epilogue: acc -> per-wave LDS (64x33 f32) -> 16B coalesced stores.
// qkv path writes q,k,v ALL row-major (v transposed later by vtrans_kernel).
template<int BMv, int MINW>
__global__ __launch_bounds__(256, MINW)
void gemm_bf16(const unsigned short* __restrict__ A,
               const unsigned short* __restrict__ Bt,
               const float* __restrict__ bias,
               float* __restrict__ C, unsigned short* __restrict__ Cbf,
               int M, int N, int K, int relu, int qkv) {
  constexpr int MFR = 4;
  constexpr int NFR = (BMv == 128) ? 4 : 2;
  __shared__ float smemf[8448];                 // 33792B: staging + epilogue reuse
  unsigned short* Al = (unsigned short*)smemf;  // 2 x BMv*32
  unsigned short* Bl = Al + 2 * BMv * 32;       // 2 x 128*32
  int t = threadIdx.x;
  int lane = t & 63, wid = t >> 6;

  int flat = blockIdx.y * gridDim.x + blockIdx.x;
  int npx = (gridDim.x * gridDim.y) >> 3;
  int w = (flat & 7) * npx + (flat >> 3);
  int bx = w % gridDim.x, by = w / gridDim.x;

  int rbase = by * BMv, cbase = bx * 128;
  int wr = (BMv == 128) ? (wid >> 1) * 64 : 0;
  int wc = (BMv == 128) ? (wid & 1) * 64 : wid * 32;

  f32x4 acc[MFR][NFR];
#pragma unroll
  for (int i = 0; i < MFR; i++)
#pragma unroll
    for (int j = 0; j < NFR; j++) acc[i][j] = (f32x4){0.f, 0.f, 0.f, 0.f};

  int srow = t >> 2;
  int sc = (((t & 3) ^ ((t >> 3) & 3)) << 3);
  const unsigned short* Ag  = A  + (long)(rbase + srow) * K + sc;
  const unsigned short* Ag2 = A  + (long)(rbase + 64 + srow) * K + sc;
  const unsigned short* Bg  = Bt + (long)(cbase + srow) * K + sc;
  const unsigned short* Bg2 = Bt + (long)(cbase + 64 + srow) * K + sc;

  auto stage = [&](int bi, int kt) {
    gload16(Ag + kt, Al + bi * BMv * 32 + t * 8);
    if constexpr (BMv == 128) gload16(Ag2 + kt, Al + bi * BMv * 32 + 2048 + t * 8);
    gload16(Bg + kt, Bl + bi * 4096 + t * 8);
    gload16(Bg2 + kt, Bl + bi * 4096 + 2048 + t * 8);
  };

  int fr = lane & 15;
  int c4 = lane >> 4;

  int nt = K >> 5;
  stage(0, 0);
  int cur = 0;
  for (int tt = 0; tt < nt; ++tt) {
    if (tt + 1 < nt) {
      stage(cur ^ 1, (tt + 1) << 5);
      if constexpr (BMv == 128)
        asm volatile("s_waitcnt vmcnt(4)" ::: "memory");
      else
        asm volatile("s_waitcnt vmcnt(3)" ::: "memory");
    } else {
      asm volatile("s_waitcnt vmcnt(0)" ::: "memory");
    }
    __builtin_amdgcn_s_barrier();

    bf16x8 a[MFR], b[NFR];
#pragma unroll
    for (int m = 0; m < MFR; m++) {
      int R = wr + m * 16 + fr;
      a[m] = *(const bf16x8*)&Al[cur * BMv * 32 + R * 32 + ((c4 ^ ((R >> 1) & 3)) << 3)];
    }
#pragma unroll
    for (int n = 0; n < NFR; n++) {
      int R = wc + n * 16 + fr;
      b[n] = *(const bf16x8*)&Bl[cur * 4096 + R * 32 + ((c4 ^ ((R >> 1) & 3)) << 3)];
    }
#pragma unroll
    for (int m = 0; m < MFR; m++)
#pragma unroll
      for (int n = 0; n < NFR; n++)
        acc[m][n] = __builtin_amdgcn_mfma_f32_16x16x32_bf16(a[m], b[n], acc[m][n], 0, 0, 0);
    __builtin_amdgcn_s_barrier();
    cur ^= 1;
  }

  // ---- LDS-staged vectorized epilogue (values identical to scalar path)
  __syncthreads();                         // staging LDS dead; all waves past
  float* wb = smemf + wid * 2112;          // per-wave 64 x 33 f32 region
  int cb0 = cbase + wc;
#pragma unroll
  for (int nh = 0; nh < NFR / 2; nh++) {
    // acc -> LDS (stride 33: conflict-free across the 4 row-groups)
#pragma unroll
    for (int mi = 0; mi < MFR; mi++)
#pragma unroll
      for (int n2 = 0; n2 < 2; n2++) {
        int n = nh * 2 + n2;
        int col = cb0 + nh * 32 + n2 * 16 + fr;
        float bv = bias ? bias[col] : 0.0f;
#pragma unroll
        for (int j = 0; j < 4; j++) {
          float v = acc[mi][n][j] + bv;
          if (relu) v = fmaxf(v, 0.0f);
          wb[(mi * 16 + (lane >> 4) * 4 + j) * 33 + n2 * 16 + fr] = v;
        }
      }
    // LDS -> global, 16B coalesced (in-wave DS ordering guards the RAW)
    if (Cbf) {
      int rl0 = lane >> 2, g = lane & 3;
#pragma unroll
      for (int i = 0; i < 4; i++) {
        int rl = i * 16 + rl0;
        long grow = rbase + wr + rl;
        int gcol = cb0 + nh * 32 + g * 8;
        unsigned short tmp[8];
#pragma unroll
        for (int e = 0; e < 8; e++) tmp[e] = f2bf(wb[rl * 33 + g * 8 + e]);
        unsigned short* dst;
        if (qkv) {
          long off = (gcol < 512) ? 0L
                     : (gcol < 1024 ? 4194304L - 512L : 8388608L - 1024L);
          dst = Cbf + off + grow * 512 + gcol;
        } else {
          dst = Cbf + grow * (long)N + gcol;
        }
        *(uint4*)dst = *(uint4*)tmp;
      }
    }
    if (C) {
      int rl0 = lane >> 3, g = lane & 7;
#pragma unroll
      for (int i = 0; i < 8; i++) {
        int rl = i * 8 + rl0;
        long grow = rbase + wr + rl;
        int gcol = cb0 + nh * 32 + g * 4;
        float4 vv = make_float4(wb[rl * 33 + g * 4],     wb[rl * 33 + g * 4 + 1],
                                wb[rl * 33 + g * 4 + 2], wb[rl * 33 + g * 4 + 3]);
        *(float4*)(C + grow * (long)N + gcol) = vv;
      }
    }
  }
}

// ------------------------------------------------------------- MFMA attention
// SPLIT-K: 512 threads = 8 waves = 4 q-groups x 2 k-halves (round-14 state).
__global__ __launch_bounds__(512, 4)
void attn_mfma(const unsigned short* __restrict__ qbf,
               const unsigned short* __restrict__ kbf,
               const unsigned short* __restrict__ vtbf,
               const unsigned int* __restrict__ maskw,
               unsigned short* __restrict__ ctxbf) {
  __shared__ unsigned short sb[4][8192];   // 4 x 16KB chunk buffers (buf = chunk)
  __shared__ float red[2][8][64];          // partial max / sum exchange
  int t = threadIdx.x;
  int lane = t & 63, w = t >> 6;           // 8 waves
  int qg = w & 3, kh = w >> 2;             // q-group, k-half
  int c = lane & 15, h = lane >> 4;

  int flat = blockIdx.y * 8 + blockIdx.x;  // grid (8, 128)
  int wk = (flat & 7) * 128 + (flat >> 3); // XCD swizzle: 16 bh per XCD
  int qt = wk & 7, bh = wk >> 3;

  long bhb = (long)bh << 15;
  int mb = bh & 15;

  unsigned int mwa[16];
#pragma unroll
  for (int i = 0; i < 16; i++)
    mwa[i] = (unsigned int)__builtin_amdgcn_readfirstlane((int)maskw[mb * 16 + i]);

  const bf16x8* qp = (const bf16x8*)(qbf + bhb + (long)(qt * 64 + qg * 16 + c) * 64);
  bf16x8 qf0 = qp[h], qf1 = qp[h + 4];

  auto stageK = [&](int gc) {
#pragma unroll
    for (int i = 0; i < 2; i++) {
      int idx = t + 512 * i;
      int kr = idx >> 3, g = idx & 7;
      gload16(kbf + bhb + (long)(gc * 128 + kr) * 64 + ((g ^ (kr & 7)) << 3),
              &sb[gc][idx * 8]);
    }
  };
  auto stageV = [&](int gc) {
#pragma unroll
    for (int i = 0; i < 2; i++) {
      int idx = t + 512 * i;
      int d = idx >> 4, g = idx & 15;
      gload16(vtbf + bhb + (long)d * 512 + gc * 128 + ((g ^ (d & 15)) << 3),
              &sb[gc][idx * 8]);
    }
  };

  stageK(0); stageK(2); stageK(1); stageK(3);

  f32x4 acc[16];
#pragma unroll
  for (int F = 0; F < 16; F++) acc[F] = (f32x4){0.f, 0.f, 0.f, 0.f};

#pragma unroll
  for (int lc = 0; lc < 2; lc++) {
    if (lc == 0) asm volatile("s_waitcnt vmcnt(4)" ::: "memory");
    else         asm volatile("s_waitcnt vmcnt(0)" ::: "memory");
    __builtin_amdgcn_s_barrier();
    const unsigned short* kb = sb[kh * 2 + lc];
#pragma unroll
    for (int f = 0; f < 8; f++) {
      int R = f * 16 + c;
      int ro = R * 64;
      bf16x8 a0 = *(const bf16x8*)&kb[ro + ((h ^ (R & 7)) << 3)];
      bf16x8 a1 = *(const bf16x8*)&kb[ro + (((h + 4) ^ (R & 7)) << 3)];
      acc[lc * 8 + f] = __builtin_amdgcn_mfma_f32_16x16x32_bf16(a0, qf0, acc[lc * 8 + f], 0, 0, 0);
      acc[lc * 8 + f] = __builtin_amdgcn_mfma_f32_16x16x32_bf16(a1, qf1, acc[lc * 8 + f], 0, 0, 0);
    }
  }
  __builtin_amdgcn_s_barrier();

  stageV(0); stageV(2); stageV(1); stageV(3);

#pragma unroll
  for (int F = 0; F < 16; F++) {
    int gc = kh * 2 + (F >> 3), f = F & 7;
    unsigned int nib = (mwa[gc * 4 + (f >> 1)] >> (((f & 1) << 4) + (h << 2))) & 0xFu;
#pragma unroll
    for (int j = 0; j < 4; j++)
      acc[F][j] = (nib & (1u << j)) ? -1e9f : acc[F][j] * 0.125f;
  }

  float mx = -3.0e38f;
#pragma unroll
  for (int F = 0; F < 16; F++)
#pragma unroll
    for (int j = 0; j < 4; j++) mx = fmaxf(mx, acc[F][j]);
  mx = fmaxf(mx, __shfl_xor(mx, 16));
  mx = fmaxf(mx, __shfl_xor(mx, 32));
  red[0][w][lane] = mx;
  __builtin_amdgcn_s_barrier();
  mx = fmaxf(mx, red[0][w ^ 4][lane]);

  float sm = 0.f;
  unsigned int pk[32];
#pragma unroll
  for (int F = 0; F < 16; F++) {
    float e0 = __expf(acc[F][0] - mx); sm += e0;
    float e1 = __expf(acc[F][1] - mx); sm += e1;
    float e2 = __expf(acc[F][2] - mx); sm += e2;
    float e3 = __expf(acc[F][3] - mx); sm += e3;
    pk[2 * F]     = (unsigned int)f2bf(e0) | ((unsigned int)f2bf(e1) << 16);
    pk[2 * F + 1] = (unsigned int)f2bf(e2) | ((unsigned int)f2bf(e3) << 16);
  }
  sm += __shfl_xor(sm, 16);
  sm += __shfl_xor(sm, 32);
  red[1][w][lane] = sm;
  __builtin_amdgcn_s_barrier();
  sm += red[1][w ^ 4][lane];

  float rs0 = 1.0f / __shfl(sm, h * 4 + 0);
  float rs1 = 1.0f / __shfl(sm, h * 4 + 1);
  float rs2 = 1.0f / __shfl(sm, h * 4 + 2);
  float rs3 = 1.0f / __shfl(sm, h * 4 + 3);

  f32x4 o[4];
#pragma unroll
  for (int n = 0; n < 4; n++) o[n] = (f32x4){0.f, 0.f, 0.f, 0.f};
  int l0 = c | ((lane & 16) << 1);
  int l1 = l0 + 16;
  bool hb = (lane & 32) != 0;

#pragma unroll
  for (int lc = 0; lc < 2; lc++) {
    if (lc == 0) asm volatile("s_waitcnt vmcnt(4)" ::: "memory");
    else         asm volatile("s_waitcnt vmcnt(0)" ::: "memory");
    __builtin_amdgcn_s_barrier();
    const unsigned short* vbuf = sb[kh * 2 + lc];
#pragma unroll
    for (int sub = 0; sub < 4; sub++) {
      int kt4 = (lc * 4 + sub) * 4;
      unsigned int a0 = __shfl((int)pk[kt4],     l0);
      unsigned int a1 = __shfl((int)pk[kt4 + 1], l0);
      unsigned int a2 = __shfl((int)pk[kt4],     l1);
      unsigned int a3 = __shfl((int)pk[kt4 + 1], l1);
      unsigned int b0 = __shfl((int)pk[kt4 + 2], l0);
      unsigned int b1 = __shfl((int)pk[kt4 + 3], l0);
      unsigned int b2 = __shfl((int)pk[kt4 + 2], l1);
      unsigned int b3 = __shfl((int)pk[kt4 + 3], l1);
      uint4 aw;
      aw.x = hb ? b0 : a0; aw.y = hb ? b1 : a1;
      aw.z = hb ? b2 : a2; aw.w = hb ? b3 : a3;
      bf16x8 af = __builtin_bit_cast(bf16x8, aw);
#pragma unroll
      for (int n = 0; n < 4; n++) {
        int dl = n * 16 + c;
        bf16x8 vf = *(const bf16x8*)&vbuf[dl * 128 + (((sub * 4 + h) ^ (dl & 15)) << 3)];
        o[n] = __builtin_amdgcn_mfma_f32_16x16x32_bf16(af, vf, o[n], 0, 0, 0);
      }
    }
  }
  __builtin_amdgcn_s_barrier();

  float* osb = (float*)sb;
  if (kh) {
#pragma unroll
    for (int n = 0; n < 4; n++)
#pragma unroll
      for (int j = 0; j < 4; j++)
        osb[((w - 4) * 64 + lane) * 16 + n * 4 + j] = o[n][j];
  }
  __builtin_amdgcn_s_barrier();
  if (!kh) {
    unsigned short* cp = ctxbf + bhb + (long)(qt * 64 + qg * 16) * 64;
#pragma unroll
    for (int n = 0; n < 4; n++) {
      float t0 = o[n][0] + osb[(w * 64 + lane) * 16 + n * 4 + 0];
      float t1 = o[n][1] + osb[(w * 64 + lane) * 16 + n * 4 + 1];
      float t2 = o[n][2] + osb[(w * 64 + lane) * 16 + n * 4 + 2];
      float t3 = o[n][3] + osb[(w * 64 + lane) * 16 + n * 4 + 3];
      cp[(h * 4 + 0) * 64 + n * 16 + c] = f2bf(t0 * rs0);
      cp[(h * 4 + 1) * 64 + n * 16 + c] = f2bf(t1 * rs1);
      cp[(h * 4 + 2) * 64 + n * 16 + c] = f2bf(t2 * rs2);
      cp[(h * 4 + 3) * 64 + n * 16 + c] = f2bf(t3 * rs3);
    }
  }
}

// ------------------------------------------------------------- LayerNorm(a+r)
__global__ __launch_bounds__(256)
void ln_kernel(const float* __restrict__ a, const float* __restrict__ r,
               const float* __restrict__ g, const float* __restrict__ be,
               float* __restrict__ out, unsigned short* __restrict__ outbf) {
  int w = threadIdx.x >> 6, lane = threadIdx.x & 63;
  long row = (long)blockIdx.x * 4 + w;
  long base = row * D_ + lane * 8;
  float4 a0 = *(const float4*)(a + base);
  float4 a1 = *(const float4*)(a + base + 4);
  float4 r0 = *(const float4*)(r + base);
  float4 r1 = *(const float4*)(r + base + 4);
  float xv[8] = {a0.x + r0.x, a0.y + r0.y, a0.z + r0.z, a0.w + r0.w,
                 a1.x + r1.x, a1.y + r1.y, a1.z + r1.z, a1.w + r1.w};
  float s = 0;
#pragma unroll
  for (int e = 0; e < 8; e++) s += xv[e];
#pragma unroll
  for (int off = 1; off < 64; off <<= 1) s += __shfl_xor(s, off);
  float m = s * (1.0f / 512.0f);
  float vs = 0;
#pragma unroll
  for (int e = 0; e < 8; e++) { float d = xv[e] - m; vs += d * d; }
#pragma unroll
  for (int off = 1; off < 64; off <<= 1) vs += __shfl_xor(vs, off);
  float rstd = 1.0f / sqrtf(vs * (1.0f / 512.0f) + 1e-5f);
  int gb = lane * 8;
  float o[8];
#pragma unroll
  for (int e = 0; e < 8; e++) o[e] = (xv[e] - m) * rstd * g[gb + e] + be[gb + e];
  *(float4*)(out + base)     = make_float4(o[0], o[1], o[2], o[3]);
  *(float4*)(out + base + 4) = make_float4(o[4], o[5], o[6], o[7]);
  ushort4 u0, u1;
  u0.x = f2bf(o[0]); u0.y = f2bf(o[1]); u0.z = f2bf(o[2]); u0.w = f2bf(o[3]);
  u1.x = f2bf(o[4]); u1.y = f2bf(o[5]); u1.z = f2bf(o[6]); u1.w = f2bf(o[7]);
  *(ushort4*)(outbf + base)     = u0;
  *(ushort4*)(outbf + base + 4) = u1;
}

// ------------------------------------------------------------- launch
extern "C" void kernel_launch(void* const* d_in, const int* in_sizes, int n_in,
                              void* d_out, int out_size, void* d_ws, size_t ws_size,
                              hipStream_t stream) {
  const int*   x    = (const int*)d_in[0];
  const int*   blen = (const int*)d_in[1];
  const float* emb  = (const float*)d_in[2];
  const float* Wq   = (const float*)d_in[3];
  const float* Wk   = (const float*)d_in[4];
  const float* Wv   = (const float*)d_in[5];
  const float* Wo   = (const float*)d_in[6];
  const float* bo   = (const float*)d_in[7];
  const float* ln1g = (const float*)d_in[8];
  const float* ln1b = (const float*)d_in[9];
  const float* W1   = (const float*)d_in[10];
  const float* b1   = (const float*)d_in[11];
  const float* W2   = (const float*)d_in[12];
  const float* b2   = (const float*)d_in[13];
  const float* ln2g = (const float*)d_in[14];
  const float* ln2b = (const float*)d_in[15];
  float* out = (float*)d_out;

  float* ws_f = (float*)d_ws;
  const long M4 = 4194304L;
  float* h   = ws_f;                 // 4M f32
  float* tmp = ws_f + M4;            // 4M f32 (Wo/W2 output; vt aliases it)
  unsigned short* U = (unsigned short*)(ws_f + 2 * M4);
  unsigned short* h_bf   = U;                    // 4M
  unsigned short* q_bf   = U + M4;               // q,k,v row-major contiguous
  unsigned short* k_bf   = U + 2 * M4;
  unsigned short* v_bf   = U + 3 * M4;
  unsigned short* ctx_bf = U + 4 * M4;
  unsigned short* vt_bf  = (unsigned short*)tmp; // vt live only vtrans->attn;
                                                 // tmp written by Wo AFTER attn
  unsigned short* mid_bf = q_bf;                 // [8192][2048] aliases q..ctx
  unsigned short* Wqkvt  = U + 5 * M4;           // 6*1536*512
  unsigned short* Wot    = Wqkvt + 6L * 1536 * 512;
  unsigned short* W1t    = Wot   + 6L * 512 * 512;
  unsigned short* W2t    = W1t   + 6L * 2048 * 512;
  unsigned int*   maskw  = (unsigned int*)(W2t + 6L * 512 * 2048);

  wconv_kernel<<<dim3(16, 16, 6), 256, 0, stream>>>(Wq, Wqkvt,            512, 512,  262144L, 786432L);
  wconv_kernel<<<dim3(16, 16, 6), 256, 0, stream>>>(Wk, Wqkvt + 262144,   512, 512,  262144L, 786432L);
  wconv_kernel<<<dim3(16, 16, 6), 256, 0, stream>>>(Wv, Wqkvt + 524288,   512, 512,  262144L, 786432L);
  wconv_kernel<<<dim3(16, 16, 6), 256, 0, stream>>>(Wo, Wot,              512, 512,  262144L, 262144L);
  wconv_kernel<<<dim3(64, 16, 6), 256, 0, stream>>>(W1, W1t,              512, 2048, 1048576L, 1048576L);
  wconv_kernel<<<dim3(16, 64, 6), 256, 0, stream>>>(W2, W2t,              2048, 512, 1048576L, 1048576L);
  mask_build_kernel<<<1, 256, 0, stream>>>(x, maskw);
  embed_pe_kernel<<<MT, 256, 0, stream>>>(x, blen, emb, h, h_bf);

  dim3 gqkv(12, 64), g2048(16, 64), g512b(4, 128), gattn(8, 128);

  for (int l = 0; l < L_; l++) {
    const unsigned short* wqkv = Wqkvt + (long)l * 1536 * 512;
    const unsigned short* wo   = Wot   + (long)l * 512 * 512;
    const unsigned short* w1   = W1t   + (long)l * 2048 * 512;
    const unsigned short* w2   = W2t   + (long)l * 512 * 2048;

    gemm_bf16<128, 2><<<gqkv, 256, 0, stream>>>(h_bf, wqkv, nullptr, nullptr, q_bf,
                                                MT, 1536, 512, 0, 1);
    vtrans_kernel<<<128, 256, 0, stream>>>(v_bf, vt_bf);
    attn_mfma<<<gattn, 512, 0, stream>>>(q_bf, k_bf, vt_bf, maskw, ctx_bf);
    gemm_bf16<64, 3><<<g512b, 256, 0, stream>>>(ctx_bf, wo, bo + (long)l * D_, tmp, nullptr,
                                                MT, 512, 512, 0, 0);
    ln_kernel<<<MT / 4, 256, 0, stream>>>(h, tmp, ln1g + (long)l * D_,
                                          ln1b + (long)l * D_, h, h_bf);
    gemm_bf16<128, 2><<<g2048, 256, 0, stream>>>(h_bf, w1, b1 + (long)l * F_, nullptr, mid_bf,
                                                 MT, 2048, 512, 1, 0);
    gemm_bf16<64, 3><<<g512b, 256, 0, stream>>>(mid_bf, w2, b2 + (long)l * D_, tmp, nullptr,
                                                MT, 512, 2048, 0, 0);
    ln_kernel<<<MT / 4, 256, 0, stream>>>(h, tmp, ln2g + (long)l * D_,
                                          ln2b + (long)l * D_,
                                          (l == L_ - 1) ? out : h, h_bf);
  }
}

// Round 18
// 898.019 us; speedup vs baseline: 1.1987x; 1.0271x over previous
//
#include <hip/hip_runtime.h>
#include <hip/hip_bf16.h>
#include <cmath>

#define B_  16
#define S_  512
#define D_  512
#define F_  2048
#define L_  6
#define MT  8192  // B_*S_ rows

typedef __attribute__((ext_vector_type(8))) __bf16 bf16x8;
typedef __attribute__((ext_vector_type(4))) float  f32x4;

__device__ __forceinline__ unsigned short f2bf(float f) {
  return __builtin_bit_cast(unsigned short, __float2bfloat16(f));
}
__device__ __forceinline__ float bf2f(unsigned short u) {
  return __builtin_bit_cast(float, ((unsigned int)u) << 16);
}

__device__ __forceinline__ void gload16(const void* g, void* l) {
  __builtin_amdgcn_global_load_lds(
      (const __attribute__((address_space(1))) void*)g,
      (__attribute__((address_space(3))) void*)l, 16, 0, 0);
}

// ------------------------------------------------------------- embed + PE
__global__ void embed_pe_kernel(const int* __restrict__ x,
                                const int* __restrict__ blen,
                                const float* __restrict__ emb,
                                float* __restrict__ h,
                                unsigned short* __restrict__ hbf) {
  int bs = blockIdx.x;
  int b = bs >> 9, s = bs & 511;
  int tok = x[bs];
  bool pe = s < blen[b];
  const float* er = emb + (long)tok * D_;
  long rb = (long)bs * D_;
  for (int d = threadIdx.x; d < D_; d += 256) {
    float e = er[d];
    if (pe) {
      float ex = (2.0f * (float)d) / 512.0f;
      float ang = (float)s / powf(10000.0f, ex);
      e += (d & 1) ? cosf(ang) : sinf(ang);
    }
    h[rb + d] = e;
    hbf[rb + d] = f2bf(e);
  }
}

// ------------------------------------------------------------- pad-mask bits
__global__ void mask_build_kernel(const int* __restrict__ x,
                                  unsigned int* __restrict__ mw) {
  int t = threadIdx.x;            // 256 threads, 1 block
  int b = t >> 4, wd = t & 15;
  unsigned int m = 0;
  for (int j = 0; j < 32; j++)
    if (x[b * 512 + wd * 32 + j] == 0) m |= (1u << j);
  mw[b * 16 + wd] = m;
}

// --------------------------------------------- weight transpose fp32->bf16
__global__ __launch_bounds__(256)
void wconv_kernel(const float* __restrict__ in, unsigned short* __restrict__ out,
                  int K, int N, long inls, long outls) {
  __shared__ float tile[32][33];
  const float* ip = in + (long)blockIdx.z * inls;
  unsigned short* op = out + (long)blockIdx.z * outls;
  int k0 = blockIdx.y * 32, n0 = blockIdx.x * 32;
  int tx = threadIdx.x & 31, ty = threadIdx.x >> 5;
  for (int i = ty; i < 32; i += 8) tile[i][tx] = ip[(long)(k0 + i) * N + n0 + tx];
  __syncthreads();
  for (int i = ty; i < 32; i += 8) op[(long)(n0 + i) * K + k0 + tx] = f2bf(tile[tx][i]);
}

// ------------------------------------------------- v row-major -> vt per block
__global__ __launch_bounds__(256)
void vtrans_kernel(const unsigned short* __restrict__ v,
                   unsigned short* __restrict__ vt) {
  __shared__ unsigned short tl[64][72];
  int bh = blockIdx.x;
  const unsigned short* ip = v + (long)bh * 32768;
  unsigned short* op = vt + (long)bh * 32768;
  int t = threadIdx.x;
  int kv = t >> 2, g = t & 3;
  int dh = t >> 2, q4 = t & 3;
  for (int c0 = 0; c0 < 512; c0 += 64) {
    __syncthreads();
    *(uint4*)&tl[kv][g * 16]     = *(const uint4*)&ip[(long)(c0 + kv) * 64 + g * 16];
    *(uint4*)&tl[kv][g * 16 + 8] = *(const uint4*)&ip[(long)(c0 + kv) * 64 + g * 16 + 8];
    __syncthreads();
    unsigned short tmp[16];
#pragma unroll
    for (int e = 0; e < 16; e++) tmp[e] = tl[q4 * 16 + e][dh];
    *(uint4*)&op[(long)dh * 512 + c0 + q4 * 16]     = *(uint4*)&tmp[0];
    *(uint4*)&op[(long)dh * 512 + c0 + q4 * 16 + 8] = *(uint4*)&tmp[8];
  }
}

// ------------------------------------------------------------- bf16 MFMA GEMM
// C[M,N] = A[M,K] @ Bt[N,K]^T. Tile BMv x 128, BK=32, 4 waves.
// 2-buffer depth-1 counted-vmcnt pipeline + LDS-staged vectorized epilogue
// (16B coalesced stores). qkv writes q,k,v row-major (vtrans builds vt).
template<int BMv, int MINW>
__global__ __launch_bounds__(256, MINW)
void gemm_bf16(const unsigned short* __restrict__ A,
               const unsigned short* __restrict__ Bt,
               const float* __restrict__ bias,
               float* __restrict__ C, unsigned short* __restrict__ Cbf,
               int M, int N, int K, int relu, int qkv) {
  constexpr int MFR = 4;
  constexpr int NFR = (BMv == 128) ? 4 : 2;
  __shared__ float smemf[8448];                 // 33792B: staging + epilogue reuse
  unsigned short* Al = (unsigned short*)smemf;  // 2 x BMv*32
  unsigned short* Bl = Al + 2 * BMv * 32;       // 2 x 128*32
  int t = threadIdx.x;
  int lane = t & 63, wid = t >> 6;

  int flat = blockIdx.y * gridDim.x + blockIdx.x;
  int npx = (gridDim.x * gridDim.y) >> 3;
  int w = (flat & 7) * npx + (flat >> 3);
  int bx = w % gridDim.x, by = w / gridDim.x;

  int rbase = by * BMv, cbase = bx * 128;
  int wr = (BMv == 128) ? (wid >> 1) * 64 : 0;
  int wc = (BMv == 128) ? (wid & 1) * 64 : wid * 32;

  f32x4 acc[MFR][NFR];
#pragma unroll
  for (int i = 0; i < MFR; i++)
#pragma unroll
    for (int j = 0; j < NFR; j++) acc[i][j] = (f32x4){0.f, 0.f, 0.f, 0.f};

  int srow = t >> 2;
  int sc = (((t & 3) ^ ((t >> 3) & 3)) << 3);
  const unsigned short* Ag  = A  + (long)(rbase + srow) * K + sc;
  const unsigned short* Ag2 = A  + (long)(rbase + 64 + srow) * K + sc;
  const unsigned short* Bg  = Bt + (long)(cbase + srow) * K + sc;
  const unsigned short* Bg2 = Bt + (long)(cbase + 64 + srow) * K + sc;

  auto stage = [&](int bi, int kt) {
    gload16(Ag + kt, Al + bi * BMv * 32 + t * 8);
    if constexpr (BMv == 128) gload16(Ag2 + kt, Al + bi * BMv * 32 + 2048 + t * 8);
    gload16(Bg + kt, Bl + bi * 4096 + t * 8);
    gload16(Bg2 + kt, Bl + bi * 4096 + 2048 + t * 8);
  };

  int fr = lane & 15;
  int c4 = lane >> 4;

  int nt = K >> 5;
  stage(0, 0);
  int cur = 0;
  for (int tt = 0; tt < nt; ++tt) {
    if (tt + 1 < nt) {
      stage(cur ^ 1, (tt + 1) << 5);
      if constexpr (BMv == 128)
        asm volatile("s_waitcnt vmcnt(4)" ::: "memory");
      else
        asm volatile("s_waitcnt vmcnt(3)" ::: "memory");
    } else {
      asm volatile("s_waitcnt vmcnt(0)" ::: "memory");
    }
    __builtin_amdgcn_s_barrier();

    bf16x8 a[MFR], b[NFR];
#pragma unroll
    for (int m = 0; m < MFR; m++) {
      int R = wr + m * 16 + fr;
      a[m] = *(const bf16x8*)&Al[cur * BMv * 32 + R * 32 + ((c4 ^ ((R >> 1) & 3)) << 3)];
    }
#pragma unroll
    for (int n = 0; n < NFR; n++) {
      int R = wc + n * 16 + fr;
      b[n] = *(const bf16x8*)&Bl[cur * 4096 + R * 32 + ((c4 ^ ((R >> 1) & 3)) << 3)];
    }
#pragma unroll
    for (int m = 0; m < MFR; m++)
#pragma unroll
      for (int n = 0; n < NFR; n++)
        acc[m][n] = __builtin_amdgcn_mfma_f32_16x16x32_bf16(a[m], b[n], acc[m][n], 0, 0, 0);
    __builtin_amdgcn_s_barrier();
    cur ^= 1;
  }

  // ---- LDS-staged vectorized epilogue (values identical to scalar path)
  __syncthreads();                         // staging LDS dead; all waves past
  float* wb = smemf + wid * 2112;          // per-wave 64 x 33 f32 region
  int cb0 = cbase + wc;
#pragma unroll
  for (int nh = 0; nh < NFR / 2; nh++) {
#pragma unroll
    for (int mi = 0; mi < MFR; mi++)
#pragma unroll
      for (int n2 = 0; n2 < 2; n2++) {
        int n = nh * 2 + n2;
        int col = cb0 + nh * 32 + n2 * 16 + fr;
        float bv = bias ? bias[col] : 0.0f;
#pragma unroll
        for (int j = 0; j < 4; j++) {
          float v = acc[mi][n][j] + bv;
          if (relu) v = fmaxf(v, 0.0f);
          wb[(mi * 16 + (lane >> 4) * 4 + j) * 33 + n2 * 16 + fr] = v;
        }
      }
    if (Cbf) {
      int rl0 = lane >> 2, g = lane & 3;
#pragma unroll
      for (int i = 0; i < 4; i++) {
        int rl = i * 16 + rl0;
        long grow = rbase + wr + rl;
        int gcol = cb0 + nh * 32 + g * 8;
        unsigned short tmp[8];
#pragma unroll
        for (int e = 0; e < 8; e++) tmp[e] = f2bf(wb[rl * 33 + g * 8 + e]);
        unsigned short* dst;
        if (qkv) {
          long off = (gcol < 512) ? 0L
                     : (gcol < 1024 ? 4194304L - 512L : 8388608L - 1024L);
          dst = Cbf + off + grow * 512 + gcol;
        } else {
          dst = Cbf + grow * (long)N + gcol;
        }
        *(uint4*)dst = *(uint4*)tmp;
      }
    }
    if (C) {
      int rl0 = lane >> 3, g = lane & 7;
#pragma unroll
      for (int i = 0; i < 8; i++) {
        int rl = i * 8 + rl0;
        long grow = rbase + wr + rl;
        int gcol = cb0 + nh * 32 + g * 4;
        float4 vv = make_float4(wb[rl * 33 + g * 4],     wb[rl * 33 + g * 4 + 1],
                                wb[rl * 33 + g * 4 + 2], wb[rl * 33 + g * 4 + 3]);
        *(float4*)(C + grow * (long)N + gcol) = vv;
      }
    }
  }
}

// ------------------------------------------------------------- MFMA attention
// SPLIT-K: 512 threads = 8 waves = 4 q-groups x 2 k-halves (round-14 state).
__global__ __launch_bounds__(512, 4)
void attn_mfma(const unsigned short* __restrict__ qbf,
               const unsigned short* __restrict__ kbf,
               const unsigned short* __restrict__ vtbf,
               const unsigned int* __restrict__ maskw,
               unsigned short* __restrict__ ctxbf) {
  __shared__ unsigned short sb[4][8192];   // 4 x 16KB chunk buffers (buf = chunk)
  __shared__ float red[2][8][64];          // partial max / sum exchange
  int t = threadIdx.x;
  int lane = t & 63, w = t >> 6;           // 8 waves
  int qg = w & 3, kh = w >> 2;             // q-group, k-half
  int c = lane & 15, h = lane >> 4;

  int flat = blockIdx.y * 8 + blockIdx.x;  // grid (8, 128)
  int wk = (flat & 7) * 128 + (flat >> 3); // XCD swizzle: 16 bh per XCD
  int qt = wk & 7, bh = wk >> 3;

  long bhb = (long)bh << 15;
  int mb = bh & 15;

  unsigned int mwa[16];
#pragma unroll
  for (int i = 0; i < 16; i++)
    mwa[i] = (unsigned int)__builtin_amdgcn_readfirstlane((int)maskw[mb * 16 + i]);

  const bf16x8* qp = (const bf16x8*)(qbf + bhb + (long)(qt * 64 + qg * 16 + c) * 64);
  bf16x8 qf0 = qp[h], qf1 = qp[h + 4];

  auto stageK = [&](int gc) {
#pragma unroll
    for (int i = 0; i < 2; i++) {
      int idx = t + 512 * i;
      int kr = idx >> 3, g = idx & 7;
      gload16(kbf + bhb + (long)(gc * 128 + kr) * 64 + ((g ^ (kr & 7)) << 3),
              &sb[gc][idx * 8]);
    }
  };
  auto stageV = [&](int gc) {
#pragma unroll
    for (int i = 0; i < 2; i++) {
      int idx = t + 512 * i;
      int d = idx >> 4, g = idx & 15;
      gload16(vtbf + bhb + (long)d * 512 + gc * 128 + ((g ^ (d & 15)) << 3),
              &sb[gc][idx * 8]);
    }
  };

  stageK(0); stageK(2); stageK(1); stageK(3);

  f32x4 acc[16];
#pragma unroll
  for (int F = 0; F < 16; F++) acc[F] = (f32x4){0.f, 0.f, 0.f, 0.f};

#pragma unroll
  for (int lc = 0; lc < 2; lc++) {
    if (lc == 0) asm volatile("s_waitcnt vmcnt(4)" ::: "memory");
    else         asm volatile("s_waitcnt vmcnt(0)" ::: "memory");
    __builtin_amdgcn_s_barrier();
    const unsigned short* kb = sb[kh * 2 + lc];
#pragma unroll
    for (int f = 0; f < 8; f++) {
      int R = f * 16 + c;
      int ro = R * 64;
      bf16x8 a0 = *(const bf16x8*)&kb[ro + ((h ^ (R & 7)) << 3)];
      bf16x8 a1 = *(const bf16x8*)&kb[ro + (((h + 4) ^ (R & 7)) << 3)];
      acc[lc * 8 + f] = __builtin_amdgcn_mfma_f32_16x16x32_bf16(a0, qf0, acc[lc * 8 + f], 0, 0, 0);
      acc[lc * 8 + f] = __builtin_amdgcn_mfma_f32_16x16x32_bf16(a1, qf1, acc[lc * 8 + f], 0, 0, 0);
    }
  }
  __builtin_amdgcn_s_barrier();

  stageV(0); stageV(2); stageV(1); stageV(3);

#pragma unroll
  for (int F = 0; F < 16; F++) {
    int gc = kh * 2 + (F >> 3), f = F & 7;
    unsigned int nib = (mwa[gc * 4 + (f >> 1)] >> (((f & 1) << 4) + (h << 2))) & 0xFu;
#pragma unroll
    for (int j = 0; j < 4; j++)
      acc[F][j] = (nib & (1u << j)) ? -1e9f : acc[F][j] * 0.125f;
  }

  float mx = -3.0e38f;
#pragma unroll
  for (int F = 0; F < 16; F++)
#pragma unroll
    for (int j = 0; j < 4; j++) mx = fmaxf(mx, acc[F][j]);
  mx = fmaxf(mx, __shfl_xor(mx, 16));
  mx = fmaxf(mx, __shfl_xor(mx, 32));
  red[0][w][lane] = mx;
  __builtin_amdgcn_s_barrier();
  mx = fmaxf(mx, red[0][w ^ 4][lane]);

  float sm = 0.f;
  unsigned int pk[32];
#pragma unroll
  for (int F = 0; F < 16; F++) {
    float e0 = __expf(acc[F][0] - mx); sm += e0;
    float e1 = __expf(acc[F][1] - mx); sm += e1;
    float e2 = __expf(acc[F][2] - mx); sm += e2;
    float e3 = __expf(acc[F][3] - mx); sm += e3;
    pk[2 * F]     = (unsigned int)f2bf(e0) | ((unsigned int)f2bf(e1) << 16);
    pk[2 * F + 1] = (unsigned int)f2bf(e2) | ((unsigned int)f2bf(e3) << 16);
  }
  sm += __shfl_xor(sm, 16);
  sm += __shfl_xor(sm, 32);
  red[1][w][lane] = sm;
  __builtin_amdgcn_s_barrier();
  sm += red[1][w ^ 4][lane];

  float rs0 = 1.0f / __shfl(sm, h * 4 + 0);
  float rs1 = 1.0f / __shfl(sm, h * 4 + 1);
  float rs2 = 1.0f / __shfl(sm, h * 4 + 2);
  float rs3 = 1.0f / __shfl(sm, h * 4 + 3);

  f32x4 o[4];
#pragma unroll
  for (int n = 0; n < 4; n++) o[n] = (f32x4){0.f, 0.f, 0.f, 0.f};
  int l0 = c | ((lane & 16) << 1);
  int l1 = l0 + 16;
  bool hb = (lane & 32) != 0;

#pragma unroll
  for (int lc = 0; lc < 2; lc++) {
    if (lc == 0) asm volatile("s_waitcnt vmcnt(4)" ::: "memory");
    else         asm volatile("s_waitcnt vmcnt(0)" ::: "memory");
    __builtin_amdgcn_s_barrier();
    const unsigned short* vbuf = sb[kh * 2 + lc];
#pragma unroll
    for (int sub = 0; sub < 4; sub++) {
      int kt4 = (lc * 4 + sub) * 4;
      unsigned int a0 = __shfl((int)pk[kt4],     l0);
      unsigned int a1 = __shfl((int)pk[kt4 + 1], l0);
      unsigned int a2 = __shfl((int)pk[kt4],     l1);
      unsigned int a3 = __shfl((int)pk[kt4 + 1], l1);
      unsigned int b0 = __shfl((int)pk[kt4 + 2], l0);
      unsigned int b1 = __shfl((int)pk[kt4 + 3], l0);
      unsigned int b2 = __shfl((int)pk[kt4 + 2], l1);
      unsigned int b3 = __shfl((int)pk[kt4 + 3], l1);
      uint4 aw;
      aw.x = hb ? b0 : a0; aw.y = hb ? b1 : a1;
      aw.z = hb ? b2 : a2; aw.w = hb ? b3 : a3;
      bf16x8 af = __builtin_bit_cast(bf16x8, aw);
#pragma unroll
      for (int n = 0; n < 4; n++) {
        int dl = n * 16 + c;
        bf16x8 vf = *(const bf16x8*)&vbuf[dl * 128 + (((sub * 4 + h) ^ (dl & 15)) << 3)];
        o[n] = __builtin_amdgcn_mfma_f32_16x16x32_bf16(af, vf, o[n], 0, 0, 0);
      }
    }
  }
  __builtin_amdgcn_s_barrier();

  float* osb = (float*)sb;
  if (kh) {
#pragma unroll
    for (int n = 0; n < 4; n++)
#pragma unroll
      for (int j = 0; j < 4; j++)
        osb[((w - 4) * 64 + lane) * 16 + n * 4 + j] = o[n][j];
  }
  __builtin_amdgcn_s_barrier();
  if (!kh) {
    unsigned short* cp = ctxbf + bhb + (long)(qt * 64 + qg * 16) * 64;
#pragma unroll
    for (int n = 0; n < 4; n++) {
      float t0 = o[n][0] + osb[(w * 64 + lane) * 16 + n * 4 + 0];
      float t1 = o[n][1] + osb[(w * 64 + lane) * 16 + n * 4 + 1];
      float t2 = o[n][2] + osb[(w * 64 + lane) * 16 + n * 4 + 2];
      float t3 = o[n][3] + osb[(w * 64 + lane) * 16 + n * 4 + 3];
      cp[(h * 4 + 0) * 64 + n * 16 + c] = f2bf(t0 * rs0);
      cp[(h * 4 + 1) * 64 + n * 16 + c] = f2bf(t1 * rs1);
      cp[(h * 4 + 2) * 64 + n * 16 + c] = f2bf(t2 * rs2);
      cp[(h * 4 + 3) * 64 + n * 16 + c] = f2bf(t3 * rs3);
    }
  }
}

// ------------------------------------------------------------- LayerNorm(a+r)
// r is now bf16 (residual branch rounded once by the producing GEMM).
__global__ __launch_bounds__(256)
void ln_kernel(const float* __restrict__ a, const unsigned short* __restrict__ r,
               const float* __restrict__ g, const float* __restrict__ be,
               float* __restrict__ out, unsigned short* __restrict__ outbf) {
  int w = threadIdx.x >> 6, lane = threadIdx.x & 63;
  long row = (long)blockIdx.x * 4 + w;
  long base = row * D_ + lane * 8;
  float4 a0 = *(const float4*)(a + base);
  float4 a1 = *(const float4*)(a + base + 4);
  uint4 ru = *(const uint4*)(r + base);          // 8 bf16
  unsigned short rr[8];
  *(uint4*)rr = ru;
  float xv[8] = {a0.x + bf2f(rr[0]), a0.y + bf2f(rr[1]),
                 a0.z + bf2f(rr[2]), a0.w + bf2f(rr[3]),
                 a1.x + bf2f(rr[4]), a1.y + bf2f(rr[5]),
                 a1.z + bf2f(rr[6]), a1.w + bf2f(rr[7])};
  float s = 0;
#pragma unroll
  for (int e = 0; e < 8; e++) s += xv[e];
#pragma unroll
  for (int off = 1; off < 64; off <<= 1) s += __shfl_xor(s, off);
  float m = s * (1.0f / 512.0f);
  float vs = 0;
#pragma unroll
  for (int e = 0; e < 8; e++) { float d = xv[e] - m; vs += d * d; }
#pragma unroll
  for (int off = 1; off < 64; off <<= 1) vs += __shfl_xor(vs, off);
  float rstd = 1.0f / sqrtf(vs * (1.0f / 512.0f) + 1e-5f);
  int gb = lane * 8;
  float o[8];
#pragma unroll
  for (int e = 0; e < 8; e++) o[e] = (xv[e] - m) * rstd * g[gb + e] + be[gb + e];
  *(float4*)(out + base)     = make_float4(o[0], o[1], o[2], o[3]);
  *(float4*)(out + base + 4) = make_float4(o[4], o[5], o[6], o[7]);
  ushort4 u0, u1;
  u0.x = f2bf(o[0]); u0.y = f2bf(o[1]); u0.z = f2bf(o[2]); u0.w = f2bf(o[3]);
  u1.x = f2bf(o[4]); u1.y = f2bf(o[5]); u1.z = f2bf(o[6]); u1.w = f2bf(o[7]);
  *(ushort4*)(outbf + base)     = u0;
  *(ushort4*)(outbf + base + 4) = u1;
}

// ------------------------------------------------------------- launch
extern "C" void kernel_launch(void* const* d_in, const int* in_sizes, int n_in,
                              void* d_out, int out_size, void* d_ws, size_t ws_size,
                              hipStream_t stream) {
  const int*   x    = (const int*)d_in[0];
  const int*   blen = (const int*)d_in[1];
  const float* emb  = (const float*)d_in[2];
  const float* Wq   = (const float*)d_in[3];
  const float* Wk   = (const float*)d_in[4];
  const float* Wv   = (const float*)d_in[5];
  const float* Wo   = (const float*)d_in[6];
  const float* bo   = (const float*)d_in[7];
  const float* ln1g = (const float*)d_in[8];
  const float* ln1b = (const float*)d_in[9];
  const float* W1   = (const float*)d_in[10];
  const float* b1   = (const float*)d_in[11];
  const float* W2   = (const float*)d_in[12];
  const float* b2   = (const float*)d_in[13];
  const float* ln2g = (const float*)d_in[14];
  const float* ln2b = (const float*)d_in[15];
  float* out = (float*)d_out;

  float* ws_f = (float*)d_ws;
  const long M4 = 4194304L;
  float* h = ws_f;                               // 4M f32
  unsigned short* X = (unsigned short*)(ws_f + M4);  // old tmp region: 8M shorts
  unsigned short* vt_bf  = X;                    // 4M shorts (vtrans -> attn)
  unsigned short* tmp_bf = X + M4;               // 4M shorts (Wo/W2 -> LN)
  unsigned short* U = (unsigned short*)(ws_f + 2 * M4);
  unsigned short* h_bf   = U;                    // 4M
  unsigned short* q_bf   = U + M4;               // q,k,v row-major contiguous
  unsigned short* k_bf   = U + 2 * M4;
  unsigned short* v_bf   = U + 3 * M4;
  unsigned short* ctx_bf = U + 4 * M4;
  unsigned short* mid_bf = q_bf;                 // [8192][2048] aliases q..ctx
  unsigned short* Wqkvt  = U + 5 * M4;           // 6*1536*512
  unsigned short* Wot    = Wqkvt + 6L * 1536 * 512;
  unsigned short* W1t    = Wot   + 6L * 512 * 512;
  unsigned short* W2t    = W1t   + 6L * 2048 * 512;
  unsigned int*   maskw  = (unsigned int*)(W2t + 6L * 512 * 2048);

  wconv_kernel<<<dim3(16, 16, 6), 256, 0, stream>>>(Wq, Wqkvt,            512, 512,  262144L, 786432L);
  wconv_kernel<<<dim3(16, 16, 6), 256, 0, stream>>>(Wk, Wqkvt + 262144,   512, 512,  262144L, 786432L);
  wconv_kernel<<<dim3(16, 16, 6), 256, 0, stream>>>(Wv, Wqkvt + 524288,   512, 512,  262144L, 786432L);
  wconv_kernel<<<dim3(16, 16, 6), 256, 0, stream>>>(Wo, Wot,              512, 512,  262144L, 262144L);
  wconv_kernel<<<dim3(64, 16, 6), 256, 0, stream>>>(W1, W1t,              512, 2048, 1048576L, 1048576L);
  wconv_kernel<<<dim3(16, 64, 6), 256, 0, stream>>>(W2, W2t,              2048, 512, 1048576L, 1048576L);
  mask_build_kernel<<<1, 256, 0, stream>>>(x, maskw);
  embed_pe_kernel<<<MT, 256, 0, stream>>>(x, blen, emb, h, h_bf);

  dim3 gqkv(12, 64), g2048(16, 64), g512b(4, 128), gattn(8, 128);

  for (int l = 0; l < L_; l++) {
    const unsigned short* wqkv = Wqkvt + (long)l * 1536 * 512;
    const unsigned short* wo   = Wot   + (long)l * 512 * 512;
    const unsigned short* w1   = W1t   + (long)l * 2048 * 512;
    const unsigned short* w2   = W2t   + (long)l * 512 * 2048;

    gemm_bf16<128, 3><<<gqkv, 256, 0, stream>>>(h_bf, wqkv, nullptr, nullptr, q_bf,
                                                MT, 1536, 512, 0, 1);
    vtrans_kernel<<<128, 256, 0, stream>>>(v_bf, vt_bf);
    attn_mfma<<<gattn, 512, 0, stream>>>(q_bf, k_bf, vt_bf, maskw, ctx_bf);
    gemm_bf16<64, 3><<<g512b, 256, 0, stream>>>(ctx_bf, wo, bo + (long)l * D_,
                                                nullptr, tmp_bf, MT, 512, 512, 0, 0);
    ln_kernel<<<MT / 4, 256, 0, stream>>>(h, tmp_bf, ln1g + (long)l * D_,
                                          ln1b + (long)l * D_, h, h_bf);
    gemm_bf16<128, 2><<<g2048, 256, 0, stream>>>(h_bf, w1, b1 + (long)l * F_, nullptr, mid_bf,
                                                 MT, 2048, 512, 1, 0);
    gemm_bf16<64, 3><<<g512b, 256, 0, stream>>>(mid_bf, w2, b2 + (long)l * D_,
                                                nullptr, tmp_bf, MT, 512, 2048, 0, 0);
    ln_kernel<<<MT / 4, 256, 0, stream>>>(h, tmp_bf, ln2g + (long)l * D_,
                                          ln2b + (long)l * D_,
                                          (l == L_ - 1) ? out : h, h_bf);
  }
}

// Round 19
// 849.661 us; speedup vs baseline: 1.2669x; 1.0569x over previous
//
#include <hip/hip_runtime.h>
#include <hip/hip_bf16.h>
#include <cmath>

#define B_  16
#define S_  512
#define D_  512
#define F_  2048
#define L_  6
#define MT  8192  // B_*S_ rows

typedef __attribute__((ext_vector_type(8))) __bf16 bf16x8;
typedef __attribute__((ext_vector_type(4))) float  f32x4;

__device__ __forceinline__ unsigned short f2bf(float f) {
  return __builtin_bit_cast(unsigned short, __float2bfloat16(f));
}
__device__ __forceinline__ float bf2f(unsigned short u) {
  return __builtin_bit_cast(float, ((unsigned int)u) << 16);
}

__device__ __forceinline__ void gload16(const void* g, void* l) {
  __builtin_amdgcn_global_load_lds(
      (const __attribute__((address_space(1))) void*)g,
      (__attribute__((address_space(3))) void*)l, 16, 0, 0);
}

// ------------------------------------------------------------- embed + PE
__global__ void embed_pe_kernel(const int* __restrict__ x,
                                const int* __restrict__ blen,
                                const float* __restrict__ emb,
                                unsigned short* __restrict__ hbf) {
  int bs = blockIdx.x;
  int b = bs >> 9, s = bs & 511;
  int tok = x[bs];
  bool pe = s < blen[b];
  const float* er = emb + (long)tok * D_;
  long rb = (long)bs * D_;
  for (int d = threadIdx.x; d < D_; d += 256) {
    float e = er[d];
    if (pe) {
      float ex = (2.0f * (float)d) / 512.0f;
      float ang = (float)s / powf(10000.0f, ex);
      e += (d & 1) ? cosf(ang) : sinf(ang);
    }
    hbf[rb + d] = f2bf(e);
  }
}

// ------------------------------------------------------------- pad-mask bits
__global__ void mask_build_kernel(const int* __restrict__ x,
                                  unsigned int* __restrict__ mw) {
  int t = threadIdx.x;            // 256 threads, 1 block
  int b = t >> 4, wd = t & 15;
  unsigned int m = 0;
  for (int j = 0; j < 32; j++)
    if (x[b * 512 + wd * 32 + j] == 0) m |= (1u << j);
  mw[b * 16 + wd] = m;
}

// --------------------------------------------- weight transpose fp32->bf16
__global__ __launch_bounds__(256)
void wconv_kernel(const float* __restrict__ in, unsigned short* __restrict__ out,
                  int K, int N, long inls, long outls) {
  __shared__ float tile[32][33];
  const float* ip = in + (long)blockIdx.z * inls;
  unsigned short* op = out + (long)blockIdx.z * outls;
  int k0 = blockIdx.y * 32, n0 = blockIdx.x * 32;
  int tx = threadIdx.x & 31, ty = threadIdx.x >> 5;
  for (int i = ty; i < 32; i += 8) tile[i][tx] = ip[(long)(k0 + i) * N + n0 + tx];
  __syncthreads();
  for (int i = ty; i < 32; i += 8) op[(long)(n0 + i) * K + k0 + tx] = f2bf(tile[tx][i]);
}

// ------------------------------------------------- v row-major -> vt per block
__global__ __launch_bounds__(256)
void vtrans_kernel(const unsigned short* __restrict__ v,
                   unsigned short* __restrict__ vt) {
  __shared__ unsigned short tl[64][72];
  int bh = blockIdx.x;
  const unsigned short* ip = v + (long)bh * 32768;
  unsigned short* op = vt + (long)bh * 32768;
  int t = threadIdx.x;
  int kv = t >> 2, g = t & 3;
  int dh = t >> 2, q4 = t & 3;
  for (int c0 = 0; c0 < 512; c0 += 64) {
    __syncthreads();
    *(uint4*)&tl[kv][g * 16]     = *(const uint4*)&ip[(long)(c0 + kv) * 64 + g * 16];
    *(uint4*)&tl[kv][g * 16 + 8] = *(const uint4*)&ip[(long)(c0 + kv) * 64 + g * 16 + 8];
    __syncthreads();
    unsigned short tmp[16];
#pragma unroll
    for (int e = 0; e < 16; e++) tmp[e] = tl[q4 * 16 + e][dh];
    *(uint4*)&op[(long)dh * 512 + c0 + q4 * 16]     = *(uint4*)&tmp[0];
    *(uint4*)&op[(long)dh * 512 + c0 + q4 * 16 + 8] = *(uint4*)&tmp[8];
  }
}

// ------------------------------------------------------------- bf16 MFMA GEMM
// C[M,N] = A[M,K] @ Bt[N,K]^T. Tile BMv x 128, BK=32, 4 waves.
// 2-buffer depth-1 counted-vmcnt pipeline + LDS-staged vectorized epilogue
// (16B coalesced stores). qkv writes q,k,v row-major (vtrans builds vt).
template<int BMv, int MINW>
__global__ __launch_bounds__(256, MINW)
void gemm_bf16(const unsigned short* __restrict__ A,
               const unsigned short* __restrict__ Bt,
               const float* __restrict__ bias,
               float* __restrict__ C, unsigned short* __restrict__ Cbf,
               int M, int N, int K, int relu, int qkv) {
  constexpr int MFR = 4;
  constexpr int NFR = (BMv == 128) ? 4 : 2;
  __shared__ float smemf[8448];                 // 33792B: staging + epilogue reuse
  unsigned short* Al = (unsigned short*)smemf;  // 2 x BMv*32
  unsigned short* Bl = Al + 2 * BMv * 32;       // 2 x 128*32
  int t = threadIdx.x;
  int lane = t & 63, wid = t >> 6;

  int flat = blockIdx.y * gridDim.x + blockIdx.x;
  int npx = (gridDim.x * gridDim.y) >> 3;
  int w = (flat & 7) * npx + (flat >> 3);
  int bx = w % gridDim.x, by = w / gridDim.x;

  int rbase = by * BMv, cbase = bx * 128;
  int wr = (BMv == 128) ? (wid >> 1) * 64 : 0;
  int wc = (BMv == 128) ? (wid & 1) * 64 : wid * 32;

  f32x4 acc[MFR][NFR];
#pragma unroll
  for (int i = 0; i < MFR; i++)
#pragma unroll
    for (int j = 0; j < NFR; j++) acc[i][j] = (f32x4){0.f, 0.f, 0.f, 0.f};

  int srow = t >> 2;
  int sc = (((t & 3) ^ ((t >> 3) & 3)) << 3);
  const unsigned short* Ag  = A  + (long)(rbase + srow) * K + sc;
  const unsigned short* Ag2 = A  + (long)(rbase + 64 + srow) * K + sc;
  const unsigned short* Bg  = Bt + (long)(cbase + srow) * K + sc;
  const unsigned short* Bg2 = Bt + (long)(cbase + 64 + srow) * K + sc;

  auto stage = [&](int bi, int kt) {
    gload16(Ag + kt, Al + bi * BMv * 32 + t * 8);
    if constexpr (BMv == 128) gload16(Ag2 + kt, Al + bi * BMv * 32 + 2048 + t * 8);
    gload16(Bg + kt, Bl + bi * 4096 + t * 8);
    gload16(Bg2 + kt, Bl + bi * 4096 + 2048 + t * 8);
  };

  int fr = lane & 15;
  int c4 = lane >> 4;

  int nt = K >> 5;
  stage(0, 0);
  int cur = 0;
  for (int tt = 0; tt < nt; ++tt) {
    if (tt + 1 < nt) {
      stage(cur ^ 1, (tt + 1) << 5);
      if constexpr (BMv == 128)
        asm volatile("s_waitcnt vmcnt(4)" ::: "memory");
      else
        asm volatile("s_waitcnt vmcnt(3)" ::: "memory");
    } else {
      asm volatile("s_waitcnt vmcnt(0)" ::: "memory");
    }
    __builtin_amdgcn_s_barrier();

    bf16x8 a[MFR], b[NFR];
#pragma unroll
    for (int m = 0; m < MFR; m++) {
      int R = wr + m * 16 + fr;
      a[m] = *(const bf16x8*)&Al[cur * BMv * 32 + R * 32 + ((c4 ^ ((R >> 1) & 3)) << 3)];
    }
#pragma unroll
    for (int n = 0; n < NFR; n++) {
      int R = wc + n * 16 + fr;
      b[n] = *(const bf16x8*)&Bl[cur * 4096 + R * 32 + ((c4 ^ ((R >> 1) & 3)) << 3)];
    }
#pragma unroll
    for (int m = 0; m < MFR; m++)
#pragma unroll
      for (int n = 0; n < NFR; n++)
        acc[m][n] = __builtin_amdgcn_mfma_f32_16x16x32_bf16(a[m], b[n], acc[m][n], 0, 0, 0);
    __builtin_amdgcn_s_barrier();
    cur ^= 1;
  }

  // ---- LDS-staged vectorized epilogue (values identical to scalar path)
  __syncthreads();                         // staging LDS dead; all waves past
  float* wb = smemf + wid * 2112;          // per-wave 64 x 33 f32 region
  int cb0 = cbase + wc;
#pragma unroll
  for (int nh = 0; nh < NFR / 2; nh++) {
#pragma unroll
    for (int mi = 0; mi < MFR; mi++)
#pragma unroll
      for (int n2 = 0; n2 < 2; n2++) {
        int n = nh * 2 + n2;
        int col = cb0 + nh * 32 + n2 * 16 + fr;
        float bv = bias ? bias[col] : 0.0f;
#pragma unroll
        for (int j = 0; j < 4; j++) {
          float v = acc[mi][n][j] + bv;
          if (relu) v = fmaxf(v, 0.0f);
          wb[(mi * 16 + (lane >> 4) * 4 + j) * 33 + n2 * 16 + fr] = v;
        }
      }
    if (Cbf) {
      int rl0 = lane >> 2, g = lane & 3;
#pragma unroll
      for (int i = 0; i < 4; i++) {
        int rl = i * 16 + rl0;
        long grow = rbase + wr + rl;
        int gcol = cb0 + nh * 32 + g * 8;
        unsigned short tmp[8];
#pragma unroll
        for (int e = 0; e < 8; e++) tmp[e] = f2bf(wb[rl * 33 + g * 8 + e]);
        unsigned short* dst;
        if (qkv) {
          long off = (gcol < 512) ? 0L
                     : (gcol < 1024 ? 4194304L - 512L : 8388608L - 1024L);
          dst = Cbf + off + grow * 512 + gcol;
        } else {
          dst = Cbf + grow * (long)N + gcol;
        }
        *(uint4*)dst = *(uint4*)tmp;
      }
    }
    if (C) {
      int rl0 = lane >> 3, g = lane & 7;
#pragma unroll
      for (int i = 0; i < 8; i++) {
        int rl = i * 8 + rl0;
        long grow = rbase + wr + rl;
        int gcol = cb0 + nh * 32 + g * 4;
        float4 vv = make_float4(wb[rl * 33 + g * 4],     wb[rl * 33 + g * 4 + 1],
                                wb[rl * 33 + g * 4 + 2], wb[rl * 33 + g * 4 + 3]);
        *(float4*)(C + grow * (long)N + gcol) = vv;
      }
    }
  }
}

// ------------------------------------------------------------- MFMA attention
// SPLIT-K: 512 threads = 8 waves = 4 q-groups x 2 k-halves (round-14 state).
__global__ __launch_bounds__(512, 4)
void attn_mfma(const unsigned short* __restrict__ qbf,
               const unsigned short* __restrict__ kbf,
               const unsigned short* __restrict__ vtbf,
               const unsigned int* __restrict__ maskw,
               unsigned short* __restrict__ ctxbf) {
  __shared__ unsigned short sb[4][8192];   // 4 x 16KB chunk buffers (buf = chunk)
  __shared__ float red[2][8][64];          // partial max / sum exchange
  int t = threadIdx.x;
  int lane = t & 63, w = t >> 6;           // 8 waves
  int qg = w & 3, kh = w >> 2;             // q-group, k-half
  int c = lane & 15, h = lane >> 4;

  int flat = blockIdx.y * 8 + blockIdx.x;  // grid (8, 128)
  int wk = (flat & 7) * 128 + (flat >> 3); // XCD swizzle: 16 bh per XCD
  int qt = wk & 7, bh = wk >> 3;

  long bhb = (long)bh << 15;
  int mb = bh & 15;

  unsigned int mwa[16];
#pragma unroll
  for (int i = 0; i < 16; i++)
    mwa[i] = (unsigned int)__builtin_amdgcn_readfirstlane((int)maskw[mb * 16 + i]);

  const bf16x8* qp = (const bf16x8*)(qbf + bhb + (long)(qt * 64 + qg * 16 + c) * 64);
  bf16x8 qf0 = qp[h], qf1 = qp[h + 4];

  auto stageK = [&](int gc) {
#pragma unroll
    for (int i = 0; i < 2; i++) {
      int idx = t + 512 * i;
      int kr = idx >> 3, g = idx & 7;
      gload16(kbf + bhb + (long)(gc * 128 + kr) * 64 + ((g ^ (kr & 7)) << 3),
              &sb[gc][idx * 8]);
    }
  };
  auto stageV = [&](int gc) {
#pragma unroll
    for (int i = 0; i < 2; i++) {
      int idx = t + 512 * i;
      int d = idx >> 4, g = idx & 15;
      gload16(vtbf + bhb + (long)d * 512 + gc * 128 + ((g ^ (d & 15)) << 3),
              &sb[gc][idx * 8]);
    }
  };

  stageK(0); stageK(2); stageK(1); stageK(3);

  f32x4 acc[16];
#pragma unroll
  for (int F = 0; F < 16; F++) acc[F] = (f32x4){0.f, 0.f, 0.f, 0.f};

#pragma unroll
  for (int lc = 0; lc < 2; lc++) {
    if (lc == 0) asm volatile("s_waitcnt vmcnt(4)" ::: "memory");
    else         asm volatile("s_waitcnt vmcnt(0)" ::: "memory");
    __builtin_amdgcn_s_barrier();
    const unsigned short* kb = sb[kh * 2 + lc];
#pragma unroll
    for (int f = 0; f < 8; f++) {
      int R = f * 16 + c;
      int ro = R * 64;
      bf16x8 a0 = *(const bf16x8*)&kb[ro + ((h ^ (R & 7)) << 3)];
      bf16x8 a1 = *(const bf16x8*)&kb[ro + (((h + 4) ^ (R & 7)) << 3)];
      acc[lc * 8 + f] = __builtin_amdgcn_mfma_f32_16x16x32_bf16(a0, qf0, acc[lc * 8 + f], 0, 0, 0);
      acc[lc * 8 + f] = __builtin_amdgcn_mfma_f32_16x16x32_bf16(a1, qf1, acc[lc * 8 + f], 0, 0, 0);
    }
  }
  __builtin_amdgcn_s_barrier();

  stageV(0); stageV(2); stageV(1); stageV(3);

#pragma unroll
  for (int F = 0; F < 16; F++) {
    int gc = kh * 2 + (F >> 3), f = F & 7;
    unsigned int nib = (mwa[gc * 4 + (f >> 1)] >> (((f & 1) << 4) + (h << 2))) & 0xFu;
#pragma unroll
    for (int j = 0; j < 4; j++)
      acc[F][j] = (nib & (1u << j)) ? -1e9f : acc[F][j] * 0.125f;
  }

  float mx = -3.0e38f;
#pragma unroll
  for (int F = 0; F < 16; F++)
#pragma unroll
    for (int j = 0; j < 4; j++) mx = fmaxf(mx, acc[F][j]);
  mx = fmaxf(mx, __shfl_xor(mx, 16));
  mx = fmaxf(mx, __shfl_xor(mx, 32));
  red[0][w][lane] = mx;
  __builtin_amdgcn_s_barrier();
  mx = fmaxf(mx, red[0][w ^ 4][lane]);

  float sm = 0.f;
  unsigned int pk[32];
#pragma unroll
  for (int F = 0; F < 16; F++) {
    float e0 = __expf(acc[F][0] - mx); sm += e0;
    float e1 = __expf(acc[F][1] - mx); sm += e1;
    float e2 = __expf(acc[F][2] - mx); sm += e2;
    float e3 = __expf(acc[F][3] - mx); sm += e3;
    pk[2 * F]     = (unsigned int)f2bf(e0) | ((unsigned int)f2bf(e1) << 16);
    pk[2 * F + 1] = (unsigned int)f2bf(e2) | ((unsigned int)f2bf(e3) << 16);
  }
  sm += __shfl_xor(sm, 16);
  sm += __shfl_xor(sm, 32);
  red[1][w][lane] = sm;
  __builtin_amdgcn_s_barrier();
  sm += red[1][w ^ 4][lane];

  float rs0 = 1.0f / __shfl(sm, h * 4 + 0);
  float rs1 = 1.0f / __shfl(sm, h * 4 + 1);
  float rs2 = 1.0f / __shfl(sm, h * 4 + 2);
  float rs3 = 1.0f / __shfl(sm, h * 4 + 3);

  f32x4 o[4];
#pragma unroll
  for (int n = 0; n < 4; n++) o[n] = (f32x4){0.f, 0.f, 0.f, 0.f};
  int l0 = c | ((lane & 16) << 1);
  int l1 = l0 + 16;
  bool hb = (lane & 32) != 0;

#pragma unroll
  for (int lc = 0; lc < 2; lc++) {
    if (lc == 0) asm volatile("s_waitcnt vmcnt(4)" ::: "memory");
    else         asm volatile("s_waitcnt vmcnt(0)" ::: "memory");
    __builtin_amdgcn_s_barrier();
    const unsigned short* vbuf = sb[kh * 2 + lc];
#pragma unroll
    for (int sub = 0; sub < 4; sub++) {
      int kt4 = (lc * 4 + sub) * 4;
      unsigned int a0 = __shfl((int)pk[kt4],     l0);
      unsigned int a1 = __shfl((int)pk[kt4 + 1], l0);
      unsigned int a2 = __shfl((int)pk[kt4],     l1);
      unsigned int a3 = __shfl((int)pk[kt4 + 1], l1);
      unsigned int b0 = __shfl((int)pk[kt4 + 2], l0);
      unsigned int b1 = __shfl((int)pk[kt4 + 3], l0);
      unsigned int b2 = __shfl((int)pk[kt4 + 2], l1);
      unsigned int b3 = __shfl((int)pk[kt4 + 3], l1);
      uint4 aw;
      aw.x = hb ? b0 : a0; aw.y = hb ? b1 : a1;
      aw.z = hb ? b2 : a2; aw.w = hb ? b3 : a3;
      bf16x8 af = __builtin_bit_cast(bf16x8, aw);
#pragma unroll
      for (int n = 0; n < 4; n++) {
        int dl = n * 16 + c;
        bf16x8 vf = *(const bf16x8*)&vbuf[dl * 128 + (((sub * 4 + h) ^ (dl & 15)) << 3)];
        o[n] = __builtin_amdgcn_mfma_f32_16x16x32_bf16(af, vf, o[n], 0, 0, 0);
      }
    }
  }
  __builtin_amdgcn_s_barrier();

  float* osb = (float*)sb;
  if (kh) {
#pragma unroll
    for (int n = 0; n < 4; n++)
#pragma unroll
      for (int j = 0; j < 4; j++)
        osb[((w - 4) * 64 + lane) * 16 + n * 4 + j] = o[n][j];
  }
  __builtin_amdgcn_s_barrier();
  if (!kh) {
    unsigned short* cp = ctxbf + bhb + (long)(qt * 64 + qg * 16) * 64;
#pragma unroll
    for (int n = 0; n < 4; n++) {
      float t0 = o[n][0] + osb[(w * 64 + lane) * 16 + n * 4 + 0];
      float t1 = o[n][1] + osb[(w * 64 + lane) * 16 + n * 4 + 1];
      float t2 = o[n][2] + osb[(w * 64 + lane) * 16 + n * 4 + 2];
      float t3 = o[n][3] + osb[(w * 64 + lane) * 16 + n * 4 + 3];
      cp[(h * 4 + 0) * 64 + n * 16 + c] = f2bf(t0 * rs0);
      cp[(h * 4 + 1) * 64 + n * 16 + c] = f2bf(t1 * rs1);
      cp[(h * 4 + 2) * 64 + n * 16 + c] = f2bf(t2 * rs2);
      cp[(h * 4 + 3) * 64 + n * 16 + c] = f2bf(t3 * rs3);
    }
  }
}

// ------------------------------------------------------------- LayerNorm(a+r)
// a and r both bf16 (residual stream kept bf16-only); f32 math inside.
// outf written only for the final layer output.
__global__ __launch_bounds__(256)
void ln_kernel(const unsigned short* __restrict__ a,
               const unsigned short* __restrict__ r,
               const float* __restrict__ g, const float* __restrict__ be,
               unsigned short* __restrict__ outbf, float* __restrict__ outf) {
  int w = threadIdx.x >> 6, lane = threadIdx.x & 63;
  long row = (long)blockIdx.x * 4 + w;
  long base = row * D_ + lane * 8;
  uint4 au = *(const uint4*)(a + base);
  uint4 ru = *(const uint4*)(r + base);
  unsigned short aa[8], rr[8];
  *(uint4*)aa = au;
  *(uint4*)rr = ru;
  float xv[8];
#pragma unroll
  for (int e = 0; e < 8; e++) xv[e] = bf2f(aa[e]) + bf2f(rr[e]);
  float s = 0;
#pragma unroll
  for (int e = 0; e < 8; e++) s += xv[e];
#pragma unroll
  for (int off = 1; off < 64; off <<= 1) s += __shfl_xor(s, off);
  float m = s * (1.0f / 512.0f);
  float vs = 0;
#pragma unroll
  for (int e = 0; e < 8; e++) { float d = xv[e] - m; vs += d * d; }
#pragma unroll
  for (int off = 1; off < 64; off <<= 1) vs += __shfl_xor(vs, off);
  float rstd = 1.0f / sqrtf(vs * (1.0f / 512.0f) + 1e-5f);
  int gb = lane * 8;
  float o[8];
#pragma unroll
  for (int e = 0; e < 8; e++) o[e] = (xv[e] - m) * rstd * g[gb + e] + be[gb + e];
  ushort4 u0, u1;
  u0.x = f2bf(o[0]); u0.y = f2bf(o[1]); u0.z = f2bf(o[2]); u0.w = f2bf(o[3]);
  u1.x = f2bf(o[4]); u1.y = f2bf(o[5]); u1.z = f2bf(o[6]); u1.w = f2bf(o[7]);
  *(ushort4*)(outbf + base)     = u0;
  *(ushort4*)(outbf + base + 4) = u1;
  if (outf) {
    *(float4*)(outf + base)     = make_float4(o[0], o[1], o[2], o[3]);
    *(float4*)(outf + base + 4) = make_float4(o[4], o[5], o[6], o[7]);
  }
}

// ------------------------------------------------------------- launch
extern "C" void kernel_launch(void* const* d_in, const int* in_sizes, int n_in,
                              void* d_out, int out_size, void* d_ws, size_t ws_size,
                              hipStream_t stream) {
  const int*   x    = (const int*)d_in[0];
  const int*   blen = (const int*)d_in[1];
  const float* emb  = (const float*)d_in[2];
  const float* Wq   = (const float*)d_in[3];
  const float* Wk   = (const float*)d_in[4];
  const float* Wv   = (const float*)d_in[5];
  const float* Wo   = (const float*)d_in[6];
  const float* bo   = (const float*)d_in[7];
  const float* ln1g = (const float*)d_in[8];
  const float* ln1b = (const float*)d_in[9];
  const float* W1   = (const float*)d_in[10];
  const float* b1   = (const float*)d_in[11];
  const float* W2   = (const float*)d_in[12];
  const float* b2   = (const float*)d_in[13];
  const float* ln2g = (const float*)d_in[14];
  const float* ln2b = (const float*)d_in[15];
  float* out = (float*)d_out;

  float* ws_f = (float*)d_ws;
  const long M4 = 4194304L;
  unsigned short* X = (unsigned short*)ws_f;     // first 8M shorts
  unsigned short* vt_bf  = X;                    // 4M shorts (vtrans -> attn)
  unsigned short* tmp_bf = X + M4;               // 4M shorts (Wo/W2 -> LN)
  unsigned short* U = (unsigned short*)(ws_f + 2 * M4);
  unsigned short* h_bf   = U;                    // 4M (residual stream, bf16-only)
  unsigned short* q_bf   = U + M4;               // q,k,v row-major contiguous
  unsigned short* k_bf   = U + 2 * M4;
  unsigned short* v_bf   = U + 3 * M4;
  unsigned short* ctx_bf = U + 4 * M4;
  unsigned short* mid_bf = q_bf;                 // [8192][2048] aliases q..ctx
  unsigned short* Wqkvt  = U + 5 * M4;           // 6*1536*512
  unsigned short* Wot    = Wqkvt + 6L * 1536 * 512;
  unsigned short* W1t    = Wot   + 6L * 512 * 512;
  unsigned short* W2t    = W1t   + 6L * 2048 * 512;
  unsigned int*   maskw  = (unsigned int*)(W2t + 6L * 512 * 2048);

  wconv_kernel<<<dim3(16, 16, 6), 256, 0, stream>>>(Wq, Wqkvt,            512, 512,  262144L, 786432L);
  wconv_kernel<<<dim3(16, 16, 6), 256, 0, stream>>>(Wk, Wqkvt + 262144,   512, 512,  262144L, 786432L);
  wconv_kernel<<<dim3(16, 16, 6), 256, 0, stream>>>(Wv, Wqkvt + 524288,   512, 512,  262144L, 786432L);
  wconv_kernel<<<dim3(16, 16, 6), 256, 0, stream>>>(Wo, Wot,              512, 512,  262144L, 262144L);
  wconv_kernel<<<dim3(64, 16, 6), 256, 0, stream>>>(W1, W1t,              512, 2048, 1048576L, 1048576L);
  wconv_kernel<<<dim3(16, 64, 6), 256, 0, stream>>>(W2, W2t,              2048, 512, 1048576L, 1048576L);
  mask_build_kernel<<<1, 256, 0, stream>>>(x, maskw);
  embed_pe_kernel<<<MT, 256, 0, stream>>>(x, blen, emb, h_bf);

  dim3 gqkv(12, 64), g2048(16, 64), g512b(4, 128), gattn(8, 128);

  for (int l = 0; l < L_; l++) {
    const unsigned short* wqkv = Wqkvt + (long)l * 1536 * 512;
    const unsigned short* wo   = Wot   + (long)l * 512 * 512;
    const unsigned short* w1   = W1t   + (long)l * 2048 * 512;
    const unsigned short* w2   = W2t   + (long)l * 512 * 2048;

    gemm_bf16<128, 3><<<gqkv, 256, 0, stream>>>(h_bf, wqkv, nullptr, nullptr, q_bf,
                                                MT, 1536, 512, 0, 1);
    vtrans_kernel<<<128, 256, 0, stream>>>(v_bf, vt_bf);
    attn_mfma<<<gattn, 512, 0, stream>>>(q_bf, k_bf, vt_bf, maskw, ctx_bf);
    gemm_bf16<64, 3><<<g512b, 256, 0, stream>>>(ctx_bf, wo, bo + (long)l * D_,
                                                nullptr, tmp_bf, MT, 512, 512, 0, 0);
    ln_kernel<<<MT / 4, 256, 0, stream>>>(h_bf, tmp_bf, ln1g + (long)l * D_,
                                          ln1b + (long)l * D_, h_bf, nullptr);
    gemm_bf16<128, 2><<<g2048, 256, 0, stream>>>(h_bf, w1, b1 + (long)l * F_, nullptr, mid_bf,
                                                 MT, 2048, 512, 1, 0);
    gemm_bf16<64, 3><<<g512b, 256, 0, stream>>>(mid_bf, w2, b2 + (long)l * D_,
                                                nullptr, tmp_bf, MT, 512, 2048, 0, 0);
    ln_kernel<<<MT / 4, 256, 0, stream>>>(h_bf, tmp_bf, ln2g + (long)l * D_,
                                          ln2b + (long)l * D_, h_bf,
                                          (l == L_ - 1) ? out : nullptr);
  }
}